// Round 16
// baseline (361.020 us; speedup 1.0000x reference)
//
#include <hip/hip_runtime.h>
#include <hip/hip_fp16.h>
#include <math.h>

// ---------------------------------------------------------------------------
// SNEA pipeline (MFMA MLPs, int8 gather payloads, factored softmax weights):
//   scalars1: layer-1 score projections; emits fp16 XH, int8 XQ, and packed
//             per-node weight tables XSP/XSN[src] = (e^sj, e^sj * rscl).
//   CSR build (merged dual-set): binned counting sort (bin=dst>>8), packed
//             recs src<<8|dl, rowptr2 = int2{start,end}.
//   agg64:   int8 gather; stage = ONE float2 gather + 2 mult per edge
//             (w = e^si * e^sj, ws = e^si * (e^sj*rscl)); den/sden in-wave;
//             epilogue agg = (sum(ws*q) - 128*sden)/den -> fp16 AGGH1.
//   mlp1f:   MFMA MLP -> tanh -> ZH fp16 + ZQ int8 + layer-2 si scores and
//             packed exp-sj tables SJP2/SJN2[src] = (e^sjL, e^sjH).
//   agg32pair: int8 gather over ZQ; stage = one float2 gather + 2 mult;
//             denL/denH in-wave; epilogue (a-128d)/(127d) -> fp16 AGGH.
//   mlp2:    MFMA [16x96]@[96x32] -> tanh -> out.
// exp(si+sj) = exp(si)*exp(sj) exactly; no segment-max anywhere (scores
// ~N(0,1), unstabilized softmax is f32-safe and mathematically identical).
// ---------------------------------------------------------------------------

#define BIN_SHIFT 8
#define BIN_SPAN  256
#define NBIN_MAX  512          // n <= 131072; src fits 24 bits

typedef _Float16 half8 __attribute__((ext_vector_type(8)));
typedef float f32x4 __attribute__((ext_vector_type(4)));

// ----------------------------- CSR build ----------------------------------

__global__ __launch_bounds__(256) void bin_hist2_kernel(
        const int* __restrict__ dP, int Ep, const int* __restrict__ dN, int En,
        int* __restrict__ binCntP, int* __restrict__ binCntN, int nbin) {
    __shared__ int lcP[NBIN_MAX], lcN[NBIN_MAX];
    for (int i = threadIdx.x; i < nbin; i += 256) { lcP[i] = 0; lcN[i] = 0; }
    __syncthreads();
    int tot = Ep + En;
    for (int i = blockIdx.x * 256 + threadIdx.x; i < tot; i += gridDim.x * 256) {
        if (i < Ep) atomicAdd(&lcP[dP[i] >> BIN_SHIFT], 1);
        else        atomicAdd(&lcN[dN[i - Ep] >> BIN_SHIFT], 1);
    }
    __syncthreads();
    for (int b = threadIdx.x; b < nbin; b += 256) {
        if (lcP[b]) atomicAdd(&binCntP[b], lcP[b]);
        if (lcN[b]) atomicAdd(&binCntN[b], lcN[b]);
    }
}

// grid = 2 blocks x 512 threads: block 0 scans P, block 1 scans N.
__global__ __launch_bounds__(512) void scan_bins2_kernel(
        const int* __restrict__ binCntP, const int* __restrict__ binCntN, int nbin,
        int* __restrict__ binBaseP, int* __restrict__ binBaseN,
        int* __restrict__ gCurP, int* __restrict__ gCurN) {
    __shared__ int sd[512];
    const int* c  = blockIdx.x ? binCntN : binCntP;
    int* bb = blockIdx.x ? binBaseN : binBaseP;
    int* gc = blockIdx.x ? gCurN : gCurP;
    int tid = threadIdx.x;
    int v = (tid < nbin) ? c[tid] : 0;
    sd[tid] = v; __syncthreads();
    for (int off = 1; off < 512; off <<= 1) {
        int t = (tid >= off) ? sd[tid - off] : 0;
        __syncthreads();
        sd[tid] += t;
        __syncthreads();
    }
    if (tid < nbin) { bb[tid] = sd[tid] - v; gc[tid] = 0; }
    if (tid == nbin - 1) bb[nbin] = sd[tid];
}

__global__ __launch_bounds__(256) void bin_scatter2_kernel(
        const int* __restrict__ srcP, const int* __restrict__ dstP, int Ep,
        const int* __restrict__ binBaseP, int* __restrict__ gCurP, int* __restrict__ binnedP,
        const int* __restrict__ srcN, const int* __restrict__ dstN, int En,
        const int* __restrict__ binBaseN, int* __restrict__ gCurN, int* __restrict__ binnedN,
        int nbin, int nbP) {
    __shared__ int lc[NBIN_MAX];
    __shared__ int lbase[NBIN_MAX];
    bool second = blockIdx.x >= nbP;
    int blk = second ? blockIdx.x - nbP : blockIdx.x;
    const int* src = second ? srcN : srcP;
    const int* dst = second ? dstN : dstP;
    int E = second ? En : Ep;
    const int* binBase = second ? binBaseN : binBaseP;
    int* gCursor = second ? gCurN : gCurP;
    int* binned  = second ? binnedN : binnedP;

    for (int i = threadIdx.x; i < nbin; i += 256) lc[i] = 0;
    __syncthreads();
    int base0 = blk * 4096 + threadIdx.x * 16;
    int rank[16], bn[16];
    #pragma unroll
    for (int k = 0; k < 16; ++k) {
        int i = base0 + k;
        if (i < E) {
            int b = dst[i] >> BIN_SHIFT;
            bn[k] = b;
            rank[k] = atomicAdd(&lc[b], 1);
        }
    }
    __syncthreads();
    for (int b = threadIdx.x; b < nbin; b += 256)
        if (lc[b]) lbase[b] = atomicAdd(&gCursor[b], lc[b]);
    __syncthreads();
    #pragma unroll
    for (int k = 0; k < 16; ++k) {
        int i = base0 + k;
        if (i < E) {
            int b = bn[k];
            int pos = binBase[b] + lbase[b] + rank[k];
            binned[pos] = (src[i] << BIN_SHIFT) | (dst[i] & (BIN_SPAN - 1));
        }
    }
}

// grid = 2*nbin: pure CSR finalize: hist -> scan -> rowptr2 -> scatter rec.
__global__ __launch_bounds__(256) void bin_finalize2_kernel(
        const int* __restrict__ binnedP, const int* __restrict__ binBaseP,
        int2* __restrict__ rp2P, int* __restrict__ esP,
        const int* __restrict__ binnedN, const int* __restrict__ binBaseN,
        int2* __restrict__ rp2N, int* __restrict__ esN,
        int n, int nbin) {
    __shared__ int hist[BIN_SPAN];
    __shared__ int curs[BIN_SPAN];
    __shared__ int psum[256];
    int b = blockIdx.x;
    bool second = b >= nbin;
    if (second) b -= nbin;
    const int* binned  = second ? binnedN : binnedP;
    const int* binBase = second ? binBaseN : binBaseP;
    int2* rowptr2 = second ? rp2N : rp2P;
    int*  esrc    = second ? esN : esP;

    int tid = threadIdx.x;
    int lo = binBase[b], hi = binBase[b + 1];
    int nodeBase = b << BIN_SHIFT;
    hist[tid] = 0;
    __syncthreads();
    for (int i = lo + tid; i < hi; i += 256)
        atomicAdd(&hist[binned[i] & (BIN_SPAN - 1)], 1);
    __syncthreads();
    int a0 = hist[tid];
    psum[tid] = a0; __syncthreads();
    for (int off = 1; off < 256; off <<= 1) {
        int t = (tid >= off) ? psum[tid - off] : 0;
        __syncthreads();
        psum[tid] += t;
        __syncthreads();
    }
    int excl = psum[tid] - a0;
    curs[tid] = excl;
    {
        int node = nodeBase + tid;
        if (node < n) rowptr2[node] = make_int2(lo + excl, lo + excl + a0);
    }
    __syncthreads();
    for (int i = lo + tid; i < hi; i += 256) {
        int rec = binned[i];
        int slot = lo + atomicAdd(&curs[rec & (BIN_SPAN - 1)], 1);
        esrc[slot] = rec;      // keep packed
    }
}

// --------------------------- scalars (layer 1) ------------------------------

__global__ __launch_bounds__(256) void scalars1_kernel(
        const float* __restrict__ x,
        const float* __restrict__ a1b, const float* __restrict__ a1u,
        float* __restrict__ S, __half* __restrict__ xh,
        unsigned char* __restrict__ xq,
        float* __restrict__ XSP, float* __restrict__ XSN, int n) {
    __shared__ float sA[256];
    for (int k = threadIdx.x; k < 256; k += blockDim.x)
        sA[k] = (k < 128) ? a1b[k] : a1u[k - 128];
    __syncthreads();
    int grp = threadIdx.x >> 4, l = threadIdx.x & 15;
    for (int row = blockIdx.x * 16 + grp; row < n; row += gridDim.x * 16) {
        const float4 v = *(const float4*)(x + (size_t)row * 64 + l * 4);
        __half2 h0 = __floats2half2_rn(v.x, v.y);
        __half2 h1 = __floats2half2_rn(v.z, v.w);
        uint2 pk = make_uint2(*(unsigned*)&h0, *(unsigned*)&h1);
        *(uint2*)(xh + (size_t)row * 64 + l * 4) = pk;
        // per-row absmax -> scale s = rowmax/127; int8 biased copy
        float am = fmaxf(fmaxf(fabsf(v.x), fabsf(v.y)), fmaxf(fabsf(v.z), fabsf(v.w)));
        #pragma unroll
        for (int off = 1; off < 16; off <<= 1) am = fmaxf(am, __shfl_xor(am, off));
        am = fmaxf(am, 1e-8f);
        float inv = 127.f / am;
        int q0 = (int)rintf(v.x * inv) + 128;
        int q1 = (int)rintf(v.y * inv) + 128;
        int q2 = (int)rintf(v.z * inv) + 128;
        int q3 = (int)rintf(v.w * inv) + 128;
        unsigned qw = ((unsigned)q0 & 255u) | (((unsigned)q1 & 255u) << 8)
                    | (((unsigned)q2 & 255u) << 16) | (((unsigned)q3 & 255u) << 24);
        *(unsigned*)(xq + (size_t)row * 64 + l * 4) = qw;
        const float4 A0 = *(const float4*)(sA + l * 4);
        const float4 A1 = *(const float4*)(sA + 64 + l * 4);
        const float4 A2 = *(const float4*)(sA + 128 + l * 4);
        const float4 A3 = *(const float4*)(sA + 192 + l * 4);
        float p0 = fmaf(v.x, A0.x, fmaf(v.y, A0.y, fmaf(v.z, A0.z, v.w * A0.w)));
        float p1 = fmaf(v.x, A1.x, fmaf(v.y, A1.y, fmaf(v.z, A1.z, v.w * A1.w)));
        float p2 = fmaf(v.x, A2.x, fmaf(v.y, A2.y, fmaf(v.z, A2.z, v.w * A2.w)));
        float p3 = fmaf(v.x, A3.x, fmaf(v.y, A3.y, fmaf(v.z, A3.z, v.w * A3.w)));
        #pragma unroll
        for (int off = 1; off < 16; off <<= 1) {
            p0 += __shfl_xor(p0, off);
            p1 += __shfl_xor(p1, off);
            p2 += __shfl_xor(p2, off);
            p3 += __shfl_xor(p3, off);
        }
        if (l == 0) {
            float s = am * (1.0f / 127.f);
            S[row] = p0;                          // si pos
            S[2 * (size_t)n + row] = p2;          // si neg
            float e1 = __expf(p1);                // e^sj pos
            float e3 = __expf(p3);                // e^sj neg
            XSP[2 * (size_t)row]     = e1;
            XSP[2 * (size_t)row + 1] = e1 * s;
            XSN[2 * (size_t)row]     = e3;
            XSN[2 * (size_t)row + 1] = e3 * s;
        }
    }
}

// ---------------- layer 1 aggregation (int8 gather, factored w) ------------

// Stage: one float2 gather; w = esi*xs.x; ws = esi*xs.y. den/sden in-wave.
__global__ __launch_bounds__(256) void agg64_kernel(
        const int2* __restrict__ rpA, const int* __restrict__ esA,
        const int2* __restrict__ rpB, const int* __restrict__ esB,
        const float* __restrict__ S,
        const float* __restrict__ XSP, const float* __restrict__ XSN,
        const unsigned char* __restrict__ xq, __half* __restrict__ AGGH1, int n) {
    int w = threadIdx.x >> 6, lane = threadIdx.x & 63;
    int idx = blockIdx.x * 4 + w;
    if (idx >= 2 * n) return;
    bool second = idx >= n;
    int node = second ? idx - n : idx;
    const int2*  rp = second ? rpB : rpA;
    const int*   es = second ? esB : esA;
    const float* si = S + (second ? 2 : 0) * (size_t)n;
    const float* xs = second ? XSN : XSP;
    float esi = __expf(si[node]);

    int2 se = rp[node];
    int start = se.x, len = se.y - se.x;
    int g3 = lane >> 3, q8 = lane & 7;
    float A0=0,A1=0,A2=0,A3=0,A4=0,A5=0,A6=0,A7=0;   // even steps
    float B0=0,B1=0,B2=0,B3=0,B4=0,B5=0,B6=0,B7=0;   // odd steps
    float den = 0.f, sden = 0.f;

    for (int cb = 0; cb < len; cb += 64) {
        int t = cb + lane;
        float wv = 0.f; int sr = 0;
        if (t < len) {
            sr = es[start + t];
            int src = (int)((unsigned)sr >> BIN_SHIFT);
            float2 x2 = *(const float2*)(xs + 2 * (size_t)src);
            float wq = esi * x2.x;
            float ws = esi * x2.y;
            wv = ws;
            den += wq;
            sden += ws;
        }
        int cl = len - cb; if (cl > 64) cl = 64;
        #pragma unroll 2
        for (int u = 0; u < cl; u += 16) {
            int e0 = u + g3, e1 = u + 8 + g3;
            float wt0 = __shfl(wv, e0);
            int   sp0 = __shfl(sr, e0);
            float wt1 = __shfl(wv, e1);
            int   sp1 = __shfl(sr, e1);
            bool v0 = e0 < cl, v1 = e1 < cl;
            uint2 pk0, pk1;
            if (v0) pk0 = *(const uint2*)(xq + (size_t)((unsigned)sp0 >> BIN_SHIFT) * 64 + q8 * 8);
            if (v1) pk1 = *(const uint2*)(xq + (size_t)((unsigned)sp1 >> BIN_SHIFT) * 64 + q8 * 8);
            if (v0) {
                float f0 = (float)( pk0.x        & 0xffu);
                float f1 = (float)((pk0.x >> 8 ) & 0xffu);
                float f2 = (float)((pk0.x >> 16) & 0xffu);
                float f3 = (float)( pk0.x >> 24        );
                float f4 = (float)( pk0.y        & 0xffu);
                float f5 = (float)((pk0.y >> 8 ) & 0xffu);
                float f6 = (float)((pk0.y >> 16) & 0xffu);
                float f7 = (float)( pk0.y >> 24        );
                A0 = fmaf(wt0, f0, A0); A1 = fmaf(wt0, f1, A1);
                A2 = fmaf(wt0, f2, A2); A3 = fmaf(wt0, f3, A3);
                A4 = fmaf(wt0, f4, A4); A5 = fmaf(wt0, f5, A5);
                A6 = fmaf(wt0, f6, A6); A7 = fmaf(wt0, f7, A7);
            }
            if (v1) {
                float f0 = (float)( pk1.x        & 0xffu);
                float f1 = (float)((pk1.x >> 8 ) & 0xffu);
                float f2 = (float)((pk1.x >> 16) & 0xffu);
                float f3 = (float)( pk1.x >> 24        );
                float f4 = (float)( pk1.y        & 0xffu);
                float f5 = (float)((pk1.y >> 8 ) & 0xffu);
                float f6 = (float)((pk1.y >> 16) & 0xffu);
                float f7 = (float)( pk1.y >> 24        );
                B0 = fmaf(wt1, f0, B0); B1 = fmaf(wt1, f1, B1);
                B2 = fmaf(wt1, f2, B2); B3 = fmaf(wt1, f3, B3);
                B4 = fmaf(wt1, f4, B4); B5 = fmaf(wt1, f5, B5);
                B6 = fmaf(wt1, f6, B6); B7 = fmaf(wt1, f7, B7);
            }
        }
    }
    float a0=A0+B0, a1=A1+B1, a2=A2+B2, a3=A3+B3;
    float a4=A4+B4, a5=A5+B5, a6=A6+B6, a7=A7+B7;
    #pragma unroll
    for (int off = 1; off < 64; off <<= 1) {
        den += __shfl_xor(den, off);
        sden += __shfl_xor(sden, off);
    }
    #pragma unroll
    for (int off = 8; off <= 32; off <<= 1) {
        a0 += __shfl_xor(a0, off); a1 += __shfl_xor(a1, off);
        a2 += __shfl_xor(a2, off); a3 += __shfl_xor(a3, off);
        a4 += __shfl_xor(a4, off); a5 += __shfl_xor(a5, off);
        a6 += __shfl_xor(a6, off); a7 += __shfl_xor(a7, off);
    }
    if (g3 == 0) {
        float r = 1.0f / fmaxf(den, 1e-16f);
        float bd = 128.f * sden;
        __half2 p0 = __floats2half2_rn((a0 - bd) * r, (a1 - bd) * r);
        __half2 p1 = __floats2half2_rn((a2 - bd) * r, (a3 - bd) * r);
        __half2 p2 = __floats2half2_rn((a4 - bd) * r, (a5 - bd) * r);
        __half2 p3 = __floats2half2_rn((a6 - bd) * r, (a7 - bd) * r);
        uint4 pk = make_uint4(*(unsigned*)&p0, *(unsigned*)&p1, *(unsigned*)&p2, *(unsigned*)&p3);
        *(uint4*)(AGGH1 + (size_t)node * 128 + (second ? 64 : 0) + q8 * 8) = pk;
    }
}

// --------------------- weight packing for MFMA MLPs ------------------------

__global__ __launch_bounds__(256) void pack_weights_kernel(
        const float* __restrict__ W1b, const float* __restrict__ W1u,
        const float* __restrict__ W2b, const float* __restrict__ W2u,
        const float* __restrict__ a2b, const float* __restrict__ a2u,
        __half* __restrict__ WPK1, __half* __restrict__ WPK2,
        __half* __restrict__ A2PK) {
    int t = threadIdx.x;
    for (int i = t; i < 8192; i += 256) {
        int j = i & 7, lane = (i >> 3) & 63, ct = (i >> 9) & 1, kk = (i >> 10) & 3, fam = i >> 12;
        const float* Wx = fam ? W1u : W1b;
        int k = kk * 32 + ((lane >> 4) << 3) + j;
        int col = ct * 16 + (lane & 15);
        WPK1[i] = __float2half(Wx[k * 32 + col]);
    }
    for (int i = t; i < 6144; i += 256) {
        int j = i & 7, lane = (i >> 3) & 63, ct = (i >> 9) & 1;
        int rest = i >> 10;                 // (fam*3 + kk)
        int kk = rest % 3, fam = rest / 3;
        const float* Wx = fam ? W2u : W2b;
        int k = kk * 32 + ((lane >> 4) << 3) + j;
        int col = ct * 16 + (lane & 15);
        WPK2[i] = __float2half(Wx[k * 32 + col]);
    }
    for (int i = t; i < 512; i += 256) {
        int j = i & 7, lane = i >> 3;
        int q = lane & 15, k = ((lane >> 4) << 3) + j;
        float v = 0.f;
        if (q == 0) v = a2b[k];
        else if (q == 1) v = a2b[32 + k];
        else if (q == 2) v = a2u[k];
        else if (q == 3) v = a2u[32 + k];
        A2PK[i] = __float2half(v);
    }
}

// ---------------- layer 1 MLP (MFMA) + tanh + layer-2 scores ---------------

#define ZPITCH 40   // halves; 80B rows keep uint4/half8 accesses 16B-aligned

__global__ __launch_bounds__(256) void mlp1f_kernel(
        const __half* __restrict__ AGGH1, const __half* __restrict__ xh,
        const __half* __restrict__ WPK1, const __half* __restrict__ A2PK,
        const float* __restrict__ b1b, const float* __restrict__ b1u,
        __half* __restrict__ zh, unsigned char* __restrict__ zq,
        float* __restrict__ S, float* __restrict__ SJP2, float* __restrict__ SJN2,
        int n, int ngrp) {
    __shared__ __half zLds[4][16][ZPITCH];
    int w = threadIdx.x >> 6, lane = threadIdx.x & 63;
    int fam = w & 1, l15 = lane & 15, lq = lane >> 4;

    half8 bfrag[4][2];
    #pragma unroll
    for (int kk = 0; kk < 4; ++kk)
        #pragma unroll
        for (int ct = 0; ct < 2; ++ct)
            bfrag[kk][ct] = *(const half8*)(WPK1 + (((fam * 4 + kk) * 2 + ct) << 9) + lane * 8);
    half8 a2frag = *(const half8*)(A2PK + lane * 8);
    const float* bb = fam ? b1u : b1b;
    float bias0 = bb[l15], bias1 = bb[16 + l15];

    int grp = blockIdx.x * 2 + (w >> 1);
    if (grp >= ngrp) return;
    int gbase = grp * 16;
    int arow = gbase + l15; if (arow >= n) arow = n - 1;
    const __half* aggRow = AGGH1 + (size_t)arow * 128 + fam * 64;
    const __half* xRow   = xh   + (size_t)arow * 64;

    f32x4 acc0 = {0.f, 0.f, 0.f, 0.f}, acc1 = {0.f, 0.f, 0.f, 0.f};
    #pragma unroll
    for (int kk = 0; kk < 2; ++kk) {
        half8 a = *(const half8*)(aggRow + kk * 32 + lq * 8);
        acc0 = __builtin_amdgcn_mfma_f32_16x16x32_f16(a, bfrag[kk][0], acc0, 0, 0, 0);
        acc1 = __builtin_amdgcn_mfma_f32_16x16x32_f16(a, bfrag[kk][1], acc1, 0, 0, 0);
    }
    #pragma unroll
    for (int kk = 2; kk < 4; ++kk) {
        half8 a = *(const half8*)(xRow + (kk - 2) * 32 + lq * 8);
        acc0 = __builtin_amdgcn_mfma_f32_16x16x32_f16(a, bfrag[kk][0], acc0, 0, 0, 0);
        acc1 = __builtin_amdgcn_mfma_f32_16x16x32_f16(a, bfrag[kk][1], acc1, 0, 0, 0);
    }
    #pragma unroll
    for (int r = 0; r < 4; ++r) {
        int row = lq * 4 + r;
        zLds[w][row][l15]      = __float2half(tanhf(acc0[r] + bias0));
        zLds[w][row][16 + l15] = __float2half(tanhf(acc1[r] + bias1));
    }
    {
        int node = lane >> 2, chunk = lane & 3;
        int gn = gbase + node;
        uint4 v = *(const uint4*)(&zLds[w][node][chunk * 8]);
        if (gn < n) *(uint4*)(zh + (size_t)gn * 64 + fam * 32 + chunk * 8) = v;
        // int8 copy: biased uint8 q = round(z*127)+128 (z in (-1,1) from tanh)
        const __half* zp = &zLds[w][node][chunk * 8];
        unsigned lo = 0, hi = 0;
        #pragma unroll
        for (int k = 0; k < 4; ++k) {
            int q = (int)rintf(__half2float(zp[k]) * 127.f) + 128;
            lo |= ((unsigned)q & 255u) << (8 * k);
        }
        #pragma unroll
        for (int k = 0; k < 4; ++k) {
            int q = (int)rintf(__half2float(zp[4 + k]) * 127.f) + 128;
            hi |= ((unsigned)q & 255u) << (8 * k);
        }
        if (gn < n) *(uint2*)(zq + (size_t)gn * 64 + fam * 32 + chunk * 8) = make_uint2(lo, hi);
    }
    {
        half8 a = *(const half8*)(&zLds[w][l15][lq * 8]);
        f32x4 sacc = {0.f, 0.f, 0.f, 0.f};
        sacc = __builtin_amdgcn_mfma_f32_16x16x32_f16(a, a2frag, sacc, 0, 0, 0);
        // fam0 (zb): q0->S0(si bp), q1->e^sj bp -> SJP2.x, q2->S6(si un),
        //            q3->e^sj un -> SJN2.x
        // fam1 (zu): q0->S2(si bn), q1->e^sj bn -> SJN2.y, q2->S4(si up),
        //            q3->e^sj up -> SJP2.y
        if (l15 < 4) {
            #pragma unroll
            for (int r = 0; r < 4; ++r) {
                int node = gbase + lq * 4 + r;
                if (node >= n) continue;
                float v = sacc[r];
                if (fam == 0) {
                    if (l15 == 0)      S[node] = v;
                    else if (l15 == 1) SJP2[2 * (size_t)node]     = __expf(v);
                    else if (l15 == 2) S[6 * (size_t)n + node] = v;
                    else               SJN2[2 * (size_t)node]     = __expf(v);
                } else {
                    if (l15 == 0)      S[2 * (size_t)n + node] = v;
                    else if (l15 == 1) SJN2[2 * (size_t)node + 1] = __expf(v);
                    else if (l15 == 2) S[4 * (size_t)n + node] = v;
                    else               SJP2[2 * (size_t)node + 1] = __expf(v);
                }
            }
        }
    }
}

// ------------- layer 2 aggregation (int8 gather, factored weights) ---------

// AGGH row layout per node: [bp(32) | bn(32) | up(32) | un(32)] fp16.
// Stage: one float2 gather; wL = esiL*sj2.x, wH = esiH*sj2.y, packed half2.
__global__ __launch_bounds__(256) void agg32pair_kernel(
        const int2* __restrict__ rpA, const int* __restrict__ esA,
        const int2* __restrict__ rpB, const int* __restrict__ esB,
        const float* __restrict__ S,
        const float* __restrict__ SJP2, const float* __restrict__ SJN2,
        const unsigned char* __restrict__ zq, __half* __restrict__ AGGH, int n) {
    int w = threadIdx.x >> 6, lane = threadIdx.x & 63;
    int idx = blockIdx.x * 4 + w;
    if (idx >= 2 * n) return;
    bool second = idx >= n;
    int node = second ? idx - n : idx;
    const int2* rp = second ? rpB : rpA;
    const int*  es = second ? esB : esA;
    // pos: L=bp(si S0) H=up(si S4).  neg: L=un(si S6) H=bn(si S2).
    const float* siL = S + (second ? 6 : 0) * (size_t)n;
    const float* siH = S + (second ? 2 : 4) * (size_t)n;
    const float* sj2 = second ? SJN2 : SJP2;
    float esiL = __expf(siL[node]), esiH = __expf(siH[node]);

    int2 se = rp[node];
    int start = se.x, len = se.y - se.x;
    int g3 = lane >> 3, q8 = lane & 7;
    bool lowf = q8 < 4;
    float A0=0,A1=0,A2=0,A3=0,A4=0,A5=0,A6=0,A7=0;
    float B0=0,B1=0,B2=0,B3=0,B4=0,B5=0,B6=0,B7=0;
    float denL = 0.f, denH = 0.f;

    for (int cb = 0; cb < len; cb += 64) {
        int t = cb + lane;
        unsigned wv = 0; int sr = 0;
        if (t < len) {
            sr = es[start + t];
            int src = (int)((unsigned)sr >> BIN_SHIFT);
            float2 e2 = *(const float2*)(sj2 + 2 * (size_t)src);
            float wL = esiL * e2.x;
            float wH = esiH * e2.y;
            denL += wL;
            denH += wH;
            __half2 h = __floats2half2_rn(wL, wH);
            wv = *(unsigned*)&h;
        }
        int cl = len - cb; if (cl > 64) cl = 64;
        #pragma unroll 2
        for (int u = 0; u < cl; u += 16) {
            int e0 = u + g3, e1 = u + 8 + g3;
            unsigned wp0 = (unsigned)__shfl((int)wv, e0);
            int      sp0 = __shfl(sr, e0);
            unsigned wp1 = (unsigned)__shfl((int)wv, e1);
            int      sp1 = __shfl(sr, e1);
            bool v0 = e0 < cl, v1 = e1 < cl;
            uint2 pk0, pk1;
            if (v0) pk0 = *(const uint2*)(zq + (size_t)((unsigned)sp0 >> BIN_SHIFT) * 64 + q8 * 8);
            if (v1) pk1 = *(const uint2*)(zq + (size_t)((unsigned)sp1 >> BIN_SHIFT) * 64 + q8 * 8);
            if (v0) {
                float2 wf = __half22float2(*(const __half2*)&wp0);
                float wt = lowf ? wf.x : wf.y;
                float f0 = (float)( pk0.x        & 0xffu);
                float f1 = (float)((pk0.x >> 8 ) & 0xffu);
                float f2 = (float)((pk0.x >> 16) & 0xffu);
                float f3 = (float)( pk0.x >> 24        );
                float f4 = (float)( pk0.y        & 0xffu);
                float f5 = (float)((pk0.y >> 8 ) & 0xffu);
                float f6 = (float)((pk0.y >> 16) & 0xffu);
                float f7 = (float)( pk0.y >> 24        );
                A0 = fmaf(wt, f0, A0); A1 = fmaf(wt, f1, A1);
                A2 = fmaf(wt, f2, A2); A3 = fmaf(wt, f3, A3);
                A4 = fmaf(wt, f4, A4); A5 = fmaf(wt, f5, A5);
                A6 = fmaf(wt, f6, A6); A7 = fmaf(wt, f7, A7);
            }
            if (v1) {
                float2 wf = __half22float2(*(const __half2*)&wp1);
                float wt = lowf ? wf.x : wf.y;
                float f0 = (float)( pk1.x        & 0xffu);
                float f1 = (float)((pk1.x >> 8 ) & 0xffu);
                float f2 = (float)((pk1.x >> 16) & 0xffu);
                float f3 = (float)( pk1.x >> 24        );
                float f4 = (float)( pk1.y        & 0xffu);
                float f5 = (float)((pk1.y >> 8 ) & 0xffu);
                float f6 = (float)((pk1.y >> 16) & 0xffu);
                float f7 = (float)( pk1.y >> 24        );
                B0 = fmaf(wt, f0, B0); B1 = fmaf(wt, f1, B1);
                B2 = fmaf(wt, f2, B2); B3 = fmaf(wt, f3, B3);
                B4 = fmaf(wt, f4, B4); B5 = fmaf(wt, f5, B5);
                B6 = fmaf(wt, f6, B6); B7 = fmaf(wt, f7, B7);
            }
        }
    }
    float a0=A0+B0, a1=A1+B1, a2=A2+B2, a3=A3+B3;
    float a4=A4+B4, a5=A5+B5, a6=A6+B6, a7=A7+B7;
    #pragma unroll
    for (int off = 1; off < 64; off <<= 1) {
        denL += __shfl_xor(denL, off);
        denH += __shfl_xor(denH, off);
    }
    #pragma unroll
    for (int off = 8; off <= 32; off <<= 1) {
        a0 += __shfl_xor(a0, off); a1 += __shfl_xor(a1, off);
        a2 += __shfl_xor(a2, off); a3 += __shfl_xor(a3, off);
        a4 += __shfl_xor(a4, off); a5 += __shfl_xor(a5, off);
        a6 += __shfl_xor(a6, off); a7 += __shfl_xor(a7, off);
    }
    if (g3 == 0) {
        float d = lowf ? denL : denH;
        float r = (d > 0.f) ? (1.0f / d) : 0.f;
        const float c = 1.0f / 127.0f;
        float bd = 128.f * d;
        float o0 = (a0 - bd) * r * c, o1 = (a1 - bd) * r * c;
        float o2 = (a2 - bd) * r * c, o3 = (a3 - bd) * r * c;
        float o4 = (a4 - bd) * r * c, o5 = (a5 - bd) * r * c;
        float o6 = (a6 - bd) * r * c, o7 = (a7 - bd) * r * c;
        __half2 p0 = __floats2half2_rn(o0, o1);
        __half2 p1 = __floats2half2_rn(o2, o3);
        __half2 p2 = __floats2half2_rn(o4, o5);
        __half2 p3 = __floats2half2_rn(o6, o7);
        uint4 pk = make_uint4(*(unsigned*)&p0, *(unsigned*)&p1, *(unsigned*)&p2, *(unsigned*)&p3);
        // pos: L=bp->0, H=up->64 ; neg: L=un->96, H=bn->32
        int base = second ? (lowf ? 96 : 32) : (lowf ? 0 : 64);
        *(uint4*)(AGGH + (size_t)node * 128 + base + (q8 & 3) * 8) = pk;
    }
}

// ------------------------------ MLP 2 (MFMA) -------------------------------

__global__ __launch_bounds__(256) void mlp2_kernel(
        const __half* __restrict__ AGGH, const __half* __restrict__ zh,
        const __half* __restrict__ WPK2,
        const float* __restrict__ b2b, const float* __restrict__ b2u,
        float* __restrict__ out, int n, int ngrp) {
    int w = threadIdx.x >> 6, lane = threadIdx.x & 63;
    int fam = w & 1, l15 = lane & 15, lq = lane >> 4;

    half8 bfrag[3][2];
    #pragma unroll
    for (int kk = 0; kk < 3; ++kk)
        #pragma unroll
        for (int ct = 0; ct < 2; ++ct)
            bfrag[kk][ct] = *(const half8*)(WPK2 + (((fam * 3 + kk) * 2 + ct) << 9) + lane * 8);
    const float* bb = fam ? b2u : b2b;
    float bias0 = bb[l15], bias1 = bb[16 + l15];

    int grp = blockIdx.x * 2 + (w >> 1);
    if (grp >= ngrp) return;
    int gbase = grp * 16;
    int arow = gbase + l15; if (arow >= n) arow = n - 1;
    const __half* aggRow = AGGH + (size_t)arow * 128 + fam * 64;
    const __half* zRow   = zh   + (size_t)arow * 64 + fam * 32;

    f32x4 acc0 = {0.f, 0.f, 0.f, 0.f}, acc1 = {0.f, 0.f, 0.f, 0.f};
    #pragma unroll
    for (int kk = 0; kk < 2; ++kk) {
        half8 a = *(const half8*)(aggRow + kk * 32 + lq * 8);
        acc0 = __builtin_amdgcn_mfma_f32_16x16x32_f16(a, bfrag[kk][0], acc0, 0, 0, 0);
        acc1 = __builtin_amdgcn_mfma_f32_16x16x32_f16(a, bfrag[kk][1], acc1, 0, 0, 0);
    }
    {
        half8 a = *(const half8*)(zRow + lq * 8);
        acc0 = __builtin_amdgcn_mfma_f32_16x16x32_f16(a, bfrag[2][0], acc0, 0, 0, 0);
        acc1 = __builtin_amdgcn_mfma_f32_16x16x32_f16(a, bfrag[2][1], acc1, 0, 0, 0);
    }
    #pragma unroll
    for (int r = 0; r < 4; ++r) {
        int node = gbase + lq * 4 + r;
        if (node < n) {
            out[(size_t)node * 64 + fam * 32 + l15]      = tanhf(acc0[r] + bias0);
            out[(size_t)node * 64 + fam * 32 + 16 + l15] = tanhf(acc1[r] + bias1);
        }
    }
}

// ------------------------------ launcher -----------------------------------

extern "C" void kernel_launch(void* const* d_in, const int* in_sizes, int n_in,
                              void* d_out, int out_size, void* d_ws, size_t ws_size,
                              hipStream_t stream) {
    const float* x   = (const float*)d_in[0];
    const int*   pos = (const int*)d_in[1];
    const int*   neg = (const int*)d_in[2];
    const float* a1b = (const float*)d_in[3];
    const float* a1u = (const float*)d_in[4];
    const float* W1b = (const float*)d_in[5];
    const float* b1b = (const float*)d_in[6];
    const float* W1u = (const float*)d_in[7];
    const float* b1u = (const float*)d_in[8];
    const float* a2b = (const float*)d_in[9];
    const float* a2u = (const float*)d_in[10];
    const float* W2b = (const float*)d_in[11];
    const float* b2b = (const float*)d_in[12];
    const float* W2u = (const float*)d_in[13];
    const float* b2u = (const float*)d_in[14];
    float* out = (float*)d_out;

    const int n  = in_sizes[0] / 64;
    const int Ep = in_sizes[1] / 2;
    const int En = in_sizes[2] / 2;
    const int* ps = pos;  const int* pd = pos + Ep;
    const int* ns = neg;  const int* nd = neg + En;
    const int nbin = (n + BIN_SPAN - 1) >> BIN_SHIFT;   // 391 for n=100000
    const int ngrp = (n + 15) / 16;

    // ws layout (4-byte words)
    unsigned* W = (unsigned*)d_ws;
    size_t o = 0;
    float* S        = (float*)(W + o); o += 8 * (size_t)n;
    int2*  rowptrP  = (int2*)(W + o);  o += 2 * (size_t)n;
    int2*  rowptrN  = (int2*)(W + o);  o += 2 * (size_t)n;
    int*   binCntP  = (int*)(W + o);   o += nbin;
    int*   binCntN  = (int*)(W + o);   o += nbin;
    int*   binBaseP = (int*)(W + o);   o += nbin + 1;
    int*   binBaseN = (int*)(W + o);   o += nbin + 1;
    int*   gCurP    = (int*)(W + o);   o += nbin;
    int*   gCurN    = (int*)(W + o);   o += nbin;
    int*   esrcP    = (int*)(W + o);   o += Ep;
    int*   esrcN    = (int*)(W + o);   o += En;
    o = (o + 1) & ~(size_t)1;
    float* XSP      = (float*)(W + o); o += 2 * (size_t)n;   // (e^sj, e^sj*rscl) pos
    float* XSN      = (float*)(W + o); o += 2 * (size_t)n;   // (e^sj, e^sj*rscl) neg
    float* SJP2     = (float*)(W + o); o += 2 * (size_t)n;   // (e^sjL, e^sjH) pos
    float* SJN2     = (float*)(W + o); o += 2 * (size_t)n;   // (e^sjL, e^sjH) neg
    o = (o + 3) & ~(size_t)3;
    __half* XH      = (__half*)(W + o); o += 32 * (size_t)n;   // x rows fp16
    __half* ZH      = (__half*)(W + o); o += 32 * (size_t)n;   // z rows fp16
    unsigned char* XQ = (unsigned char*)(W + o); o += 16 * (size_t)n; // x rows u8
    unsigned char* ZQ = (unsigned char*)(W + o); o += 16 * (size_t)n; // z rows u8
    o = (o + 3) & ~(size_t)3;
    __half* WPK1    = (__half*)(W + o); o += 4096;
    __half* WPK2    = (__half*)(W + o); o += 3072;
    __half* A2PK    = (__half*)(W + o); o += 256;
    o = (o + 3) & ~(size_t)3;
    __half* AGGH    = (__half*)(W + o); o += 64 * (size_t)n;   // [n][128] fp16
    int*   binnedP  = (int*)AGGH;        // CSR-build scratch aliases AGGH
    int*   binnedN  = binnedP + Ep;
    __half* AGGH1   = AGGH;              // layer-1 agg rows [aggP|aggN]

    const int B = 256;
    const int aggBlocks = (2 * n + 3) / 4;
    const int mlpBlocks = (ngrp + 1) / 2;
    const int nbP = (Ep + 4095) / 4096, nbN = (En + 4095) / 4096;
    auto gcap = [](long t, int b) { long g = (t + b - 1) / b; return (int)(g < 2048 ? g : 2048); };

    // -------- scalars + pack + merged CSR build ------
    hipMemsetAsync(binCntP, 0, 2 * (size_t)nbin * sizeof(int), stream);
    pack_weights_kernel<<<1, 256, 0, stream>>>(W1b, W1u, W2b, W2u, a2b, a2u,
                                               WPK1, WPK2, A2PK);
    scalars1_kernel<<<512, B, 0, stream>>>(x, a1b, a1u, S, XH, XQ, XSP, XSN, n);
    bin_hist2_kernel<<<gcap((long)Ep + En, B), B, 0, stream>>>(pd, Ep, nd, En,
                                                               binCntP, binCntN, nbin);
    scan_bins2_kernel<<<2, 512, 0, stream>>>(binCntP, binCntN, nbin,
                                             binBaseP, binBaseN, gCurP, gCurN);
    bin_scatter2_kernel<<<nbP + nbN, 256, 0, stream>>>(
        ps, pd, Ep, binBaseP, gCurP, binnedP,
        ns, nd, En, binBaseN, gCurN, binnedN, nbin, nbP);
    bin_finalize2_kernel<<<2 * nbin, 256, 0, stream>>>(
        binnedP, binBaseP, rowptrP, esrcP,
        binnedN, binBaseN, rowptrN, esrcN, n, nbin);

    // ---------------- Layer 1 ----------------
    agg64_kernel<<<aggBlocks, 256, 0, stream>>>(
        rowptrP, esrcP, rowptrN, esrcN, S, XSP, XSN, XQ, AGGH1, n);
    mlp1f_kernel<<<mlpBlocks, 256, 0, stream>>>(AGGH1, XH, WPK1, A2PK,
                                                b1b, b1u, ZH, ZQ, S, SJP2, SJN2,
                                                n, ngrp);

    // ---------------- Layer 2 ----------------
    agg32pair_kernel<<<aggBlocks, 256, 0, stream>>>(
        rowptrP, esrcP, rowptrN, esrcN, S, SJP2, SJN2, ZQ, AGGH, n);
    mlp2_kernel<<<mlpBlocks, 256, 0, stream>>>(AGGH, ZH, WPK2, b2b, b2u, out, n, ngrp);
}

// Round 17
// 273.156 us; speedup vs baseline: 1.3217x; 1.3217x over previous
//
#include <hip/hip_runtime.h>
#include <hip/hip_fp16.h>
#include <math.h>

// ---------------------------------------------------------------------------
// SNEA pipeline (MFMA MLPs, int8 gathers, factored weights, 8-lane groups):
//   scalars1: layer-1 score projections; emits fp16 XH, int8 XQ, and packed
//             per-node weight tables XSP/XSN[src] = (e^sj, e^sj * rscl).
//   CSR build (merged dual-set): binned counting sort (bin=dst>>8), packed
//             recs src<<8|dl, rowptr2 = int2{start,end}.
//   agg64 / agg32pair: 8-LANE GROUP PER NODE (8 nodes/wave): lanes of a group
//             broadcast-load rec + weight pair, gather their 8B slice of the
//             64B int8 row, accumulate per-lane; den computed redundantly in
//             every lane -> NO cross-lane reductions, no shuffles at all.
//   mlp1f:   MFMA MLP -> tanh -> ZH fp16 + ZQ int8 + layer-2 si scores and
//             packed exp-sj tables SJP2/SJN2[src] = (e^sjL, e^sjH).
//   mlp2:    MFMA [16x96]@[96x32] -> tanh -> out.
// exp(si+sj) = exp(si)*exp(sj) exactly; no segment-max anywhere (scores
// ~N(0,1), unstabilized softmax is f32-safe and mathematically identical).
// ---------------------------------------------------------------------------

#define BIN_SHIFT 8
#define BIN_SPAN  256
#define NBIN_MAX  512          // n <= 131072; src fits 24 bits

typedef _Float16 half8 __attribute__((ext_vector_type(8)));
typedef float f32x4 __attribute__((ext_vector_type(4)));

// ----------------------------- CSR build ----------------------------------

__global__ __launch_bounds__(256) void bin_hist2_kernel(
        const int* __restrict__ dP, int Ep, const int* __restrict__ dN, int En,
        int* __restrict__ binCntP, int* __restrict__ binCntN, int nbin) {
    __shared__ int lcP[NBIN_MAX], lcN[NBIN_MAX];
    for (int i = threadIdx.x; i < nbin; i += 256) { lcP[i] = 0; lcN[i] = 0; }
    __syncthreads();
    int tot = Ep + En;
    for (int i = blockIdx.x * 256 + threadIdx.x; i < tot; i += gridDim.x * 256) {
        if (i < Ep) atomicAdd(&lcP[dP[i] >> BIN_SHIFT], 1);
        else        atomicAdd(&lcN[dN[i - Ep] >> BIN_SHIFT], 1);
    }
    __syncthreads();
    for (int b = threadIdx.x; b < nbin; b += 256) {
        if (lcP[b]) atomicAdd(&binCntP[b], lcP[b]);
        if (lcN[b]) atomicAdd(&binCntN[b], lcN[b]);
    }
}

// grid = 2 blocks x 512 threads: block 0 scans P, block 1 scans N.
__global__ __launch_bounds__(512) void scan_bins2_kernel(
        const int* __restrict__ binCntP, const int* __restrict__ binCntN, int nbin,
        int* __restrict__ binBaseP, int* __restrict__ binBaseN,
        int* __restrict__ gCurP, int* __restrict__ gCurN) {
    __shared__ int sd[512];
    const int* c  = blockIdx.x ? binCntN : binCntP;
    int* bb = blockIdx.x ? binBaseN : binBaseP;
    int* gc = blockIdx.x ? gCurN : gCurP;
    int tid = threadIdx.x;
    int v = (tid < nbin) ? c[tid] : 0;
    sd[tid] = v; __syncthreads();
    for (int off = 1; off < 512; off <<= 1) {
        int t = (tid >= off) ? sd[tid - off] : 0;
        __syncthreads();
        sd[tid] += t;
        __syncthreads();
    }
    if (tid < nbin) { bb[tid] = sd[tid] - v; gc[tid] = 0; }
    if (tid == nbin - 1) bb[nbin] = sd[tid];
}

__global__ __launch_bounds__(256) void bin_scatter2_kernel(
        const int* __restrict__ srcP, const int* __restrict__ dstP, int Ep,
        const int* __restrict__ binBaseP, int* __restrict__ gCurP, int* __restrict__ binnedP,
        const int* __restrict__ srcN, const int* __restrict__ dstN, int En,
        const int* __restrict__ binBaseN, int* __restrict__ gCurN, int* __restrict__ binnedN,
        int nbin, int nbP) {
    __shared__ int lc[NBIN_MAX];
    __shared__ int lbase[NBIN_MAX];
    bool second = blockIdx.x >= nbP;
    int blk = second ? blockIdx.x - nbP : blockIdx.x;
    const int* src = second ? srcN : srcP;
    const int* dst = second ? dstN : dstP;
    int E = second ? En : Ep;
    const int* binBase = second ? binBaseN : binBaseP;
    int* gCursor = second ? gCurN : gCurP;
    int* binned  = second ? binnedN : binnedP;

    for (int i = threadIdx.x; i < nbin; i += 256) lc[i] = 0;
    __syncthreads();
    int base0 = blk * 4096 + threadIdx.x * 16;
    int rank[16], bn[16];
    #pragma unroll
    for (int k = 0; k < 16; ++k) {
        int i = base0 + k;
        if (i < E) {
            int b = dst[i] >> BIN_SHIFT;
            bn[k] = b;
            rank[k] = atomicAdd(&lc[b], 1);
        }
    }
    __syncthreads();
    for (int b = threadIdx.x; b < nbin; b += 256)
        if (lc[b]) lbase[b] = atomicAdd(&gCursor[b], lc[b]);
    __syncthreads();
    #pragma unroll
    for (int k = 0; k < 16; ++k) {
        int i = base0 + k;
        if (i < E) {
            int b = bn[k];
            int pos = binBase[b] + lbase[b] + rank[k];
            binned[pos] = (src[i] << BIN_SHIFT) | (dst[i] & (BIN_SPAN - 1));
        }
    }
}

// grid = 2*nbin: pure CSR finalize: hist -> scan -> rowptr2 -> scatter rec.
__global__ __launch_bounds__(256) void bin_finalize2_kernel(
        const int* __restrict__ binnedP, const int* __restrict__ binBaseP,
        int2* __restrict__ rp2P, int* __restrict__ esP,
        const int* __restrict__ binnedN, const int* __restrict__ binBaseN,
        int2* __restrict__ rp2N, int* __restrict__ esN,
        int n, int nbin) {
    __shared__ int hist[BIN_SPAN];
    __shared__ int curs[BIN_SPAN];
    __shared__ int psum[256];
    int b = blockIdx.x;
    bool second = b >= nbin;
    if (second) b -= nbin;
    const int* binned  = second ? binnedN : binnedP;
    const int* binBase = second ? binBaseN : binBaseP;
    int2* rowptr2 = second ? rp2N : rp2P;
    int*  esrc    = second ? esN : esP;

    int tid = threadIdx.x;
    int lo = binBase[b], hi = binBase[b + 1];
    int nodeBase = b << BIN_SHIFT;
    hist[tid] = 0;
    __syncthreads();
    for (int i = lo + tid; i < hi; i += 256)
        atomicAdd(&hist[binned[i] & (BIN_SPAN - 1)], 1);
    __syncthreads();
    int a0 = hist[tid];
    psum[tid] = a0; __syncthreads();
    for (int off = 1; off < 256; off <<= 1) {
        int t = (tid >= off) ? psum[tid - off] : 0;
        __syncthreads();
        psum[tid] += t;
        __syncthreads();
    }
    int excl = psum[tid] - a0;
    curs[tid] = excl;
    {
        int node = nodeBase + tid;
        if (node < n) rowptr2[node] = make_int2(lo + excl, lo + excl + a0);
    }
    __syncthreads();
    for (int i = lo + tid; i < hi; i += 256) {
        int rec = binned[i];
        int slot = lo + atomicAdd(&curs[rec & (BIN_SPAN - 1)], 1);
        esrc[slot] = rec;      // keep packed
    }
}

// --------------------------- scalars (layer 1) ------------------------------

__global__ __launch_bounds__(256) void scalars1_kernel(
        const float* __restrict__ x,
        const float* __restrict__ a1b, const float* __restrict__ a1u,
        float* __restrict__ S, __half* __restrict__ xh,
        unsigned char* __restrict__ xq,
        float* __restrict__ XSP, float* __restrict__ XSN, int n) {
    __shared__ float sA[256];
    for (int k = threadIdx.x; k < 256; k += blockDim.x)
        sA[k] = (k < 128) ? a1b[k] : a1u[k - 128];
    __syncthreads();
    int grp = threadIdx.x >> 4, l = threadIdx.x & 15;
    for (int row = blockIdx.x * 16 + grp; row < n; row += gridDim.x * 16) {
        const float4 v = *(const float4*)(x + (size_t)row * 64 + l * 4);
        __half2 h0 = __floats2half2_rn(v.x, v.y);
        __half2 h1 = __floats2half2_rn(v.z, v.w);
        uint2 pk = make_uint2(*(unsigned*)&h0, *(unsigned*)&h1);
        *(uint2*)(xh + (size_t)row * 64 + l * 4) = pk;
        // per-row absmax -> scale s = rowmax/127; int8 biased copy
        float am = fmaxf(fmaxf(fabsf(v.x), fabsf(v.y)), fmaxf(fabsf(v.z), fabsf(v.w)));
        #pragma unroll
        for (int off = 1; off < 16; off <<= 1) am = fmaxf(am, __shfl_xor(am, off));
        am = fmaxf(am, 1e-8f);
        float inv = 127.f / am;
        int q0 = (int)rintf(v.x * inv) + 128;
        int q1 = (int)rintf(v.y * inv) + 128;
        int q2 = (int)rintf(v.z * inv) + 128;
        int q3 = (int)rintf(v.w * inv) + 128;
        unsigned qw = ((unsigned)q0 & 255u) | (((unsigned)q1 & 255u) << 8)
                    | (((unsigned)q2 & 255u) << 16) | (((unsigned)q3 & 255u) << 24);
        *(unsigned*)(xq + (size_t)row * 64 + l * 4) = qw;
        const float4 A0 = *(const float4*)(sA + l * 4);
        const float4 A1 = *(const float4*)(sA + 64 + l * 4);
        const float4 A2 = *(const float4*)(sA + 128 + l * 4);
        const float4 A3 = *(const float4*)(sA + 192 + l * 4);
        float p0 = fmaf(v.x, A0.x, fmaf(v.y, A0.y, fmaf(v.z, A0.z, v.w * A0.w)));
        float p1 = fmaf(v.x, A1.x, fmaf(v.y, A1.y, fmaf(v.z, A1.z, v.w * A1.w)));
        float p2 = fmaf(v.x, A2.x, fmaf(v.y, A2.y, fmaf(v.z, A2.z, v.w * A2.w)));
        float p3 = fmaf(v.x, A3.x, fmaf(v.y, A3.y, fmaf(v.z, A3.z, v.w * A3.w)));
        #pragma unroll
        for (int off = 1; off < 16; off <<= 1) {
            p0 += __shfl_xor(p0, off);
            p1 += __shfl_xor(p1, off);
            p2 += __shfl_xor(p2, off);
            p3 += __shfl_xor(p3, off);
        }
        if (l == 0) {
            float s = am * (1.0f / 127.f);
            S[row] = p0;                          // si pos
            S[2 * (size_t)n + row] = p2;          // si neg
            float e1 = __expf(p1);                // e^sj pos
            float e3 = __expf(p3);                // e^sj neg
            XSP[2 * (size_t)row]     = e1;
            XSP[2 * (size_t)row + 1] = e1 * s;
            XSN[2 * (size_t)row]     = e3;
            XSN[2 * (size_t)row + 1] = e3 * s;
        }
    }
}

// -------- layer 1 aggregation (8-lane group per node, no reductions) -------

__global__ __launch_bounds__(256) void agg64_kernel(
        const int2* __restrict__ rpA, const int* __restrict__ esA,
        const int2* __restrict__ rpB, const int* __restrict__ esB,
        const float* __restrict__ S,
        const float* __restrict__ XSP, const float* __restrict__ XSN,
        const unsigned char* __restrict__ xq, __half* __restrict__ AGGH1, int n) {
    int gid = blockIdx.x * 32 + (threadIdx.x >> 3);
    int L = threadIdx.x & 7;
    if (gid >= 2 * n) return;
    bool second = gid >= n;
    int node = second ? gid - n : gid;
    const int2*  rp = second ? rpB : rpA;
    const int*   es = second ? esB : esA;
    const float* si = S + (second ? 2 : 0) * (size_t)n;
    const float* xs = second ? XSN : XSP;
    float esi = __expf(si[node]);

    int2 se = rp[node];
    int start = se.x, len = se.y - se.x;
    float a0=0,a1=0,a2=0,a3=0,a4=0,a5=0,a6=0,a7=0;
    float den = 0.f, sden = 0.f;

    int e = 0;
    for (; e + 2 <= len; e += 2) {
        int rec0 = es[start + e];
        int rec1 = es[start + e + 1];
        int src0 = (int)((unsigned)rec0 >> BIN_SHIFT);
        int src1 = (int)((unsigned)rec1 >> BIN_SHIFT);
        float2 x20 = *(const float2*)(xs + 2 * (size_t)src0);
        float2 x21 = *(const float2*)(xs + 2 * (size_t)src1);
        uint2 pk0 = *(const uint2*)(xq + (size_t)src0 * 64 + L * 8);
        uint2 pk1 = *(const uint2*)(xq + (size_t)src1 * 64 + L * 8);
        float ws0 = esi * x20.y;
        float ws1 = esi * x21.y;
        den  += esi * x20.x + esi * x21.x;
        sden += ws0 + ws1;
        a0 = fmaf(ws0, (float)( pk0.x        & 0xffu), a0);
        a1 = fmaf(ws0, (float)((pk0.x >> 8 ) & 0xffu), a1);
        a2 = fmaf(ws0, (float)((pk0.x >> 16) & 0xffu), a2);
        a3 = fmaf(ws0, (float)( pk0.x >> 24        ), a3);
        a4 = fmaf(ws0, (float)( pk0.y        & 0xffu), a4);
        a5 = fmaf(ws0, (float)((pk0.y >> 8 ) & 0xffu), a5);
        a6 = fmaf(ws0, (float)((pk0.y >> 16) & 0xffu), a6);
        a7 = fmaf(ws0, (float)( pk0.y >> 24        ), a7);
        a0 = fmaf(ws1, (float)( pk1.x        & 0xffu), a0);
        a1 = fmaf(ws1, (float)((pk1.x >> 8 ) & 0xffu), a1);
        a2 = fmaf(ws1, (float)((pk1.x >> 16) & 0xffu), a2);
        a3 = fmaf(ws1, (float)( pk1.x >> 24        ), a3);
        a4 = fmaf(ws1, (float)( pk1.y        & 0xffu), a4);
        a5 = fmaf(ws1, (float)((pk1.y >> 8 ) & 0xffu), a5);
        a6 = fmaf(ws1, (float)((pk1.y >> 16) & 0xffu), a6);
        a7 = fmaf(ws1, (float)( pk1.y >> 24        ), a7);
    }
    if (e < len) {
        int rec0 = es[start + e];
        int src0 = (int)((unsigned)rec0 >> BIN_SHIFT);
        float2 x20 = *(const float2*)(xs + 2 * (size_t)src0);
        uint2 pk0 = *(const uint2*)(xq + (size_t)src0 * 64 + L * 8);
        float ws0 = esi * x20.y;
        den  += esi * x20.x;
        sden += ws0;
        a0 = fmaf(ws0, (float)( pk0.x        & 0xffu), a0);
        a1 = fmaf(ws0, (float)((pk0.x >> 8 ) & 0xffu), a1);
        a2 = fmaf(ws0, (float)((pk0.x >> 16) & 0xffu), a2);
        a3 = fmaf(ws0, (float)( pk0.x >> 24        ), a3);
        a4 = fmaf(ws0, (float)( pk0.y        & 0xffu), a4);
        a5 = fmaf(ws0, (float)((pk0.y >> 8 ) & 0xffu), a5);
        a6 = fmaf(ws0, (float)((pk0.y >> 16) & 0xffu), a6);
        a7 = fmaf(ws0, (float)( pk0.y >> 24        ), a7);
    }
    float r = 1.0f / fmaxf(den, 1e-16f);
    float bd = 128.f * sden;
    __half2 p0 = __floats2half2_rn((a0 - bd) * r, (a1 - bd) * r);
    __half2 p1 = __floats2half2_rn((a2 - bd) * r, (a3 - bd) * r);
    __half2 p2 = __floats2half2_rn((a4 - bd) * r, (a5 - bd) * r);
    __half2 p3 = __floats2half2_rn((a6 - bd) * r, (a7 - bd) * r);
    uint4 pk = make_uint4(*(unsigned*)&p0, *(unsigned*)&p1, *(unsigned*)&p2, *(unsigned*)&p3);
    *(uint4*)(AGGH1 + (size_t)node * 128 + (second ? 64 : 0) + L * 8) = pk;
}

// --------------------- weight packing for MFMA MLPs ------------------------

__global__ __launch_bounds__(256) void pack_weights_kernel(
        const float* __restrict__ W1b, const float* __restrict__ W1u,
        const float* __restrict__ W2b, const float* __restrict__ W2u,
        const float* __restrict__ a2b, const float* __restrict__ a2u,
        __half* __restrict__ WPK1, __half* __restrict__ WPK2,
        __half* __restrict__ A2PK) {
    int t = threadIdx.x;
    for (int i = t; i < 8192; i += 256) {
        int j = i & 7, lane = (i >> 3) & 63, ct = (i >> 9) & 1, kk = (i >> 10) & 3, fam = i >> 12;
        const float* Wx = fam ? W1u : W1b;
        int k = kk * 32 + ((lane >> 4) << 3) + j;
        int col = ct * 16 + (lane & 15);
        WPK1[i] = __float2half(Wx[k * 32 + col]);
    }
    for (int i = t; i < 6144; i += 256) {
        int j = i & 7, lane = (i >> 3) & 63, ct = (i >> 9) & 1;
        int rest = i >> 10;                 // (fam*3 + kk)
        int kk = rest % 3, fam = rest / 3;
        const float* Wx = fam ? W2u : W2b;
        int k = kk * 32 + ((lane >> 4) << 3) + j;
        int col = ct * 16 + (lane & 15);
        WPK2[i] = __float2half(Wx[k * 32 + col]);
    }
    for (int i = t; i < 512; i += 256) {
        int j = i & 7, lane = i >> 3;
        int q = lane & 15, k = ((lane >> 4) << 3) + j;
        float v = 0.f;
        if (q == 0) v = a2b[k];
        else if (q == 1) v = a2b[32 + k];
        else if (q == 2) v = a2u[k];
        else if (q == 3) v = a2u[32 + k];
        A2PK[i] = __float2half(v);
    }
}

// ---------------- layer 1 MLP (MFMA) + tanh + layer-2 scores ---------------

#define ZPITCH 40   // halves; 80B rows keep uint4/half8 accesses 16B-aligned

__global__ __launch_bounds__(256) void mlp1f_kernel(
        const __half* __restrict__ AGGH1, const __half* __restrict__ xh,
        const __half* __restrict__ WPK1, const __half* __restrict__ A2PK,
        const float* __restrict__ b1b, const float* __restrict__ b1u,
        __half* __restrict__ zh, unsigned char* __restrict__ zq,
        float* __restrict__ S, float* __restrict__ SJP2, float* __restrict__ SJN2,
        int n, int ngrp) {
    __shared__ __half zLds[4][16][ZPITCH];
    int w = threadIdx.x >> 6, lane = threadIdx.x & 63;
    int fam = w & 1, l15 = lane & 15, lq = lane >> 4;

    half8 bfrag[4][2];
    #pragma unroll
    for (int kk = 0; kk < 4; ++kk)
        #pragma unroll
        for (int ct = 0; ct < 2; ++ct)
            bfrag[kk][ct] = *(const half8*)(WPK1 + (((fam * 4 + kk) * 2 + ct) << 9) + lane * 8);
    half8 a2frag = *(const half8*)(A2PK + lane * 8);
    const float* bb = fam ? b1u : b1b;
    float bias0 = bb[l15], bias1 = bb[16 + l15];

    int grp = blockIdx.x * 2 + (w >> 1);
    if (grp >= ngrp) return;
    int gbase = grp * 16;
    int arow = gbase + l15; if (arow >= n) arow = n - 1;
    const __half* aggRow = AGGH1 + (size_t)arow * 128 + fam * 64;
    const __half* xRow   = xh   + (size_t)arow * 64;

    f32x4 acc0 = {0.f, 0.f, 0.f, 0.f}, acc1 = {0.f, 0.f, 0.f, 0.f};
    #pragma unroll
    for (int kk = 0; kk < 2; ++kk) {
        half8 a = *(const half8*)(aggRow + kk * 32 + lq * 8);
        acc0 = __builtin_amdgcn_mfma_f32_16x16x32_f16(a, bfrag[kk][0], acc0, 0, 0, 0);
        acc1 = __builtin_amdgcn_mfma_f32_16x16x32_f16(a, bfrag[kk][1], acc1, 0, 0, 0);
    }
    #pragma unroll
    for (int kk = 2; kk < 4; ++kk) {
        half8 a = *(const half8*)(xRow + (kk - 2) * 32 + lq * 8);
        acc0 = __builtin_amdgcn_mfma_f32_16x16x32_f16(a, bfrag[kk][0], acc0, 0, 0, 0);
        acc1 = __builtin_amdgcn_mfma_f32_16x16x32_f16(a, bfrag[kk][1], acc1, 0, 0, 0);
    }
    #pragma unroll
    for (int r = 0; r < 4; ++r) {
        int row = lq * 4 + r;
        zLds[w][row][l15]      = __float2half(tanhf(acc0[r] + bias0));
        zLds[w][row][16 + l15] = __float2half(tanhf(acc1[r] + bias1));
    }
    {
        int node = lane >> 2, chunk = lane & 3;
        int gn = gbase + node;
        uint4 v = *(const uint4*)(&zLds[w][node][chunk * 8]);
        if (gn < n) *(uint4*)(zh + (size_t)gn * 64 + fam * 32 + chunk * 8) = v;
        // int8 copy: biased uint8 q = round(z*127)+128 (z in (-1,1) from tanh)
        const __half* zp = &zLds[w][node][chunk * 8];
        unsigned lo = 0, hi = 0;
        #pragma unroll
        for (int k = 0; k < 4; ++k) {
            int q = (int)rintf(__half2float(zp[k]) * 127.f) + 128;
            lo |= ((unsigned)q & 255u) << (8 * k);
        }
        #pragma unroll
        for (int k = 0; k < 4; ++k) {
            int q = (int)rintf(__half2float(zp[4 + k]) * 127.f) + 128;
            hi |= ((unsigned)q & 255u) << (8 * k);
        }
        if (gn < n) *(uint2*)(zq + (size_t)gn * 64 + fam * 32 + chunk * 8) = make_uint2(lo, hi);
    }
    {
        half8 a = *(const half8*)(&zLds[w][l15][lq * 8]);
        f32x4 sacc = {0.f, 0.f, 0.f, 0.f};
        sacc = __builtin_amdgcn_mfma_f32_16x16x32_f16(a, a2frag, sacc, 0, 0, 0);
        // fam0 (zb): q0->S0(si bp), q1->e^sj bp -> SJP2.x, q2->S6(si un),
        //            q3->e^sj un -> SJN2.x
        // fam1 (zu): q0->S2(si bn), q1->e^sj bn -> SJN2.y, q2->S4(si up),
        //            q3->e^sj up -> SJP2.y
        if (l15 < 4) {
            #pragma unroll
            for (int r = 0; r < 4; ++r) {
                int node = gbase + lq * 4 + r;
                if (node >= n) continue;
                float v = sacc[r];
                if (fam == 0) {
                    if (l15 == 0)      S[node] = v;
                    else if (l15 == 1) SJP2[2 * (size_t)node]     = __expf(v);
                    else if (l15 == 2) S[6 * (size_t)n + node] = v;
                    else               SJN2[2 * (size_t)node]     = __expf(v);
                } else {
                    if (l15 == 0)      S[2 * (size_t)n + node] = v;
                    else if (l15 == 1) SJN2[2 * (size_t)node + 1] = __expf(v);
                    else if (l15 == 2) S[4 * (size_t)n + node] = v;
                    else               SJP2[2 * (size_t)node + 1] = __expf(v);
                }
            }
        }
    }
}

// ------- layer 2 aggregation (8-lane group per node, no reductions) --------

// AGGH row layout per node: [bp(32) | bn(32) | up(32) | un(32)] fp16.
// Lane L<4 accumulates L family (bytes L*8 of zq = zb cols), L>=4 H family.
__global__ __launch_bounds__(256) void agg32pair_kernel(
        const int2* __restrict__ rpA, const int* __restrict__ esA,
        const int2* __restrict__ rpB, const int* __restrict__ esB,
        const float* __restrict__ S,
        const float* __restrict__ SJP2, const float* __restrict__ SJN2,
        const unsigned char* __restrict__ zq, __half* __restrict__ AGGH, int n) {
    int gid = blockIdx.x * 32 + (threadIdx.x >> 3);
    int L = threadIdx.x & 7;
    if (gid >= 2 * n) return;
    bool second = gid >= n;
    int node = second ? gid - n : gid;
    const int2* rp = second ? rpB : rpA;
    const int*  es = second ? esB : esA;
    // pos: L=bp(si S0) H=up(si S4).  neg: L=un(si S6) H=bn(si S2).
    const float* siL = S + (second ? 6 : 0) * (size_t)n;
    const float* siH = S + (second ? 2 : 4) * (size_t)n;
    const float* sj2 = second ? SJN2 : SJP2;
    float esiL = __expf(siL[node]), esiH = __expf(siH[node]);
    bool lowf = L < 4;
    float esiF = lowf ? esiL : esiH;

    int2 se = rp[node];
    int start = se.x, len = se.y - se.x;
    float a0=0,a1=0,a2=0,a3=0,a4=0,a5=0,a6=0,a7=0;
    float denL = 0.f, denH = 0.f;

    int e = 0;
    for (; e + 2 <= len; e += 2) {
        int rec0 = es[start + e];
        int rec1 = es[start + e + 1];
        int src0 = (int)((unsigned)rec0 >> BIN_SHIFT);
        int src1 = (int)((unsigned)rec1 >> BIN_SHIFT);
        float2 e20 = *(const float2*)(sj2 + 2 * (size_t)src0);
        float2 e21 = *(const float2*)(sj2 + 2 * (size_t)src1);
        uint2 pk0 = *(const uint2*)(zq + (size_t)src0 * 64 + L * 8);
        uint2 pk1 = *(const uint2*)(zq + (size_t)src1 * 64 + L * 8);
        denL += esiL * e20.x + esiL * e21.x;
        denH += esiH * e20.y + esiH * e21.y;
        float wt0 = esiF * (lowf ? e20.x : e20.y);
        float wt1 = esiF * (lowf ? e21.x : e21.y);
        a0 = fmaf(wt0, (float)( pk0.x        & 0xffu), a0);
        a1 = fmaf(wt0, (float)((pk0.x >> 8 ) & 0xffu), a1);
        a2 = fmaf(wt0, (float)((pk0.x >> 16) & 0xffu), a2);
        a3 = fmaf(wt0, (float)( pk0.x >> 24        ), a3);
        a4 = fmaf(wt0, (float)( pk0.y        & 0xffu), a4);
        a5 = fmaf(wt0, (float)((pk0.y >> 8 ) & 0xffu), a5);
        a6 = fmaf(wt0, (float)((pk0.y >> 16) & 0xffu), a6);
        a7 = fmaf(wt0, (float)( pk0.y >> 24        ), a7);
        a0 = fmaf(wt1, (float)( pk1.x        & 0xffu), a0);
        a1 = fmaf(wt1, (float)((pk1.x >> 8 ) & 0xffu), a1);
        a2 = fmaf(wt1, (float)((pk1.x >> 16) & 0xffu), a2);
        a3 = fmaf(wt1, (float)( pk1.x >> 24        ), a3);
        a4 = fmaf(wt1, (float)( pk1.y        & 0xffu), a4);
        a5 = fmaf(wt1, (float)((pk1.y >> 8 ) & 0xffu), a5);
        a6 = fmaf(wt1, (float)((pk1.y >> 16) & 0xffu), a6);
        a7 = fmaf(wt1, (float)( pk1.y >> 24        ), a7);
    }
    if (e < len) {
        int rec0 = es[start + e];
        int src0 = (int)((unsigned)rec0 >> BIN_SHIFT);
        float2 e20 = *(const float2*)(sj2 + 2 * (size_t)src0);
        uint2 pk0 = *(const uint2*)(zq + (size_t)src0 * 64 + L * 8);
        denL += esiL * e20.x;
        denH += esiH * e20.y;
        float wt0 = esiF * (lowf ? e20.x : e20.y);
        a0 = fmaf(wt0, (float)( pk0.x        & 0xffu), a0);
        a1 = fmaf(wt0, (float)((pk0.x >> 8 ) & 0xffu), a1);
        a2 = fmaf(wt0, (float)((pk0.x >> 16) & 0xffu), a2);
        a3 = fmaf(wt0, (float)( pk0.x >> 24        ), a3);
        a4 = fmaf(wt0, (float)( pk0.y        & 0xffu), a4);
        a5 = fmaf(wt0, (float)((pk0.y >> 8 ) & 0xffu), a5);
        a6 = fmaf(wt0, (float)((pk0.y >> 16) & 0xffu), a6);
        a7 = fmaf(wt0, (float)( pk0.y >> 24        ), a7);
    }
    float d = lowf ? denL : denH;
    float r = (d > 0.f) ? (1.0f / d) : 0.f;
    const float c = 1.0f / 127.0f;
    float bd = 128.f * d;
    float o0 = (a0 - bd) * r * c, o1 = (a1 - bd) * r * c;
    float o2 = (a2 - bd) * r * c, o3 = (a3 - bd) * r * c;
    float o4 = (a4 - bd) * r * c, o5 = (a5 - bd) * r * c;
    float o6 = (a6 - bd) * r * c, o7 = (a7 - bd) * r * c;
    __half2 p0 = __floats2half2_rn(o0, o1);
    __half2 p1 = __floats2half2_rn(o2, o3);
    __half2 p2 = __floats2half2_rn(o4, o5);
    __half2 p3 = __floats2half2_rn(o6, o7);
    uint4 pk = make_uint4(*(unsigned*)&p0, *(unsigned*)&p1, *(unsigned*)&p2, *(unsigned*)&p3);
    // pos: L=bp->0, H=up->64 ; neg: L=un->96, H=bn->32
    int base = second ? (lowf ? 96 : 32) : (lowf ? 0 : 64);
    *(uint4*)(AGGH + (size_t)node * 128 + base + (L & 3) * 8) = pk;
}

// ------------------------------ MLP 2 (MFMA) -------------------------------

__global__ __launch_bounds__(256) void mlp2_kernel(
        const __half* __restrict__ AGGH, const __half* __restrict__ zh,
        const __half* __restrict__ WPK2,
        const float* __restrict__ b2b, const float* __restrict__ b2u,
        float* __restrict__ out, int n, int ngrp) {
    int w = threadIdx.x >> 6, lane = threadIdx.x & 63;
    int fam = w & 1, l15 = lane & 15, lq = lane >> 4;

    half8 bfrag[3][2];
    #pragma unroll
    for (int kk = 0; kk < 3; ++kk)
        #pragma unroll
        for (int ct = 0; ct < 2; ++ct)
            bfrag[kk][ct] = *(const half8*)(WPK2 + (((fam * 3 + kk) * 2 + ct) << 9) + lane * 8);
    const float* bb = fam ? b2u : b2b;
    float bias0 = bb[l15], bias1 = bb[16 + l15];

    int grp = blockIdx.x * 2 + (w >> 1);
    if (grp >= ngrp) return;
    int gbase = grp * 16;
    int arow = gbase + l15; if (arow >= n) arow = n - 1;
    const __half* aggRow = AGGH + (size_t)arow * 128 + fam * 64;
    const __half* zRow   = zh   + (size_t)arow * 64 + fam * 32;

    f32x4 acc0 = {0.f, 0.f, 0.f, 0.f}, acc1 = {0.f, 0.f, 0.f, 0.f};
    #pragma unroll
    for (int kk = 0; kk < 2; ++kk) {
        half8 a = *(const half8*)(aggRow + kk * 32 + lq * 8);
        acc0 = __builtin_amdgcn_mfma_f32_16x16x32_f16(a, bfrag[kk][0], acc0, 0, 0, 0);
        acc1 = __builtin_amdgcn_mfma_f32_16x16x32_f16(a, bfrag[kk][1], acc1, 0, 0, 0);
    }
    {
        half8 a = *(const half8*)(zRow + lq * 8);
        acc0 = __builtin_amdgcn_mfma_f32_16x16x32_f16(a, bfrag[2][0], acc0, 0, 0, 0);
        acc1 = __builtin_amdgcn_mfma_f32_16x16x32_f16(a, bfrag[2][1], acc1, 0, 0, 0);
    }
    #pragma unroll
    for (int r = 0; r < 4; ++r) {
        int node = gbase + lq * 4 + r;
        if (node < n) {
            out[(size_t)node * 64 + fam * 32 + l15]      = tanhf(acc0[r] + bias0);
            out[(size_t)node * 64 + fam * 32 + 16 + l15] = tanhf(acc1[r] + bias1);
        }
    }
}

// ------------------------------ launcher -----------------------------------

extern "C" void kernel_launch(void* const* d_in, const int* in_sizes, int n_in,
                              void* d_out, int out_size, void* d_ws, size_t ws_size,
                              hipStream_t stream) {
    const float* x   = (const float*)d_in[0];
    const int*   pos = (const int*)d_in[1];
    const int*   neg = (const int*)d_in[2];
    const float* a1b = (const float*)d_in[3];
    const float* a1u = (const float*)d_in[4];
    const float* W1b = (const float*)d_in[5];
    const float* b1b = (const float*)d_in[6];
    const float* W1u = (const float*)d_in[7];
    const float* b1u = (const float*)d_in[8];
    const float* a2b = (const float*)d_in[9];
    const float* a2u = (const float*)d_in[10];
    const float* W2b = (const float*)d_in[11];
    const float* b2b = (const float*)d_in[12];
    const float* W2u = (const float*)d_in[13];
    const float* b2u = (const float*)d_in[14];
    float* out = (float*)d_out;

    const int n  = in_sizes[0] / 64;
    const int Ep = in_sizes[1] / 2;
    const int En = in_sizes[2] / 2;
    const int* ps = pos;  const int* pd = pos + Ep;
    const int* ns = neg;  const int* nd = neg + En;
    const int nbin = (n + BIN_SPAN - 1) >> BIN_SHIFT;   // 391 for n=100000
    const int ngrp = (n + 15) / 16;

    // ws layout (4-byte words)
    unsigned* W = (unsigned*)d_ws;
    size_t o = 0;
    float* S        = (float*)(W + o); o += 8 * (size_t)n;
    int2*  rowptrP  = (int2*)(W + o);  o += 2 * (size_t)n;
    int2*  rowptrN  = (int2*)(W + o);  o += 2 * (size_t)n;
    int*   binCntP  = (int*)(W + o);   o += nbin;
    int*   binCntN  = (int*)(W + o);   o += nbin;
    int*   binBaseP = (int*)(W + o);   o += nbin + 1;
    int*   binBaseN = (int*)(W + o);   o += nbin + 1;
    int*   gCurP    = (int*)(W + o);   o += nbin;
    int*   gCurN    = (int*)(W + o);   o += nbin;
    int*   esrcP    = (int*)(W + o);   o += Ep;
    int*   esrcN    = (int*)(W + o);   o += En;
    o = (o + 1) & ~(size_t)1;
    float* XSP      = (float*)(W + o); o += 2 * (size_t)n;   // (e^sj, e^sj*rscl) pos
    float* XSN      = (float*)(W + o); o += 2 * (size_t)n;   // (e^sj, e^sj*rscl) neg
    float* SJP2     = (float*)(W + o); o += 2 * (size_t)n;   // (e^sjL, e^sjH) pos
    float* SJN2     = (float*)(W + o); o += 2 * (size_t)n;   // (e^sjL, e^sjH) neg
    o = (o + 3) & ~(size_t)3;
    __half* XH      = (__half*)(W + o); o += 32 * (size_t)n;   // x rows fp16
    __half* ZH      = (__half*)(W + o); o += 32 * (size_t)n;   // z rows fp16
    unsigned char* XQ = (unsigned char*)(W + o); o += 16 * (size_t)n; // x rows u8
    unsigned char* ZQ = (unsigned char*)(W + o); o += 16 * (size_t)n; // z rows u8
    o = (o + 3) & ~(size_t)3;
    __half* WPK1    = (__half*)(W + o); o += 4096;
    __half* WPK2    = (__half*)(W + o); o += 3072;
    __half* A2PK    = (__half*)(W + o); o += 256;
    o = (o + 3) & ~(size_t)3;
    __half* AGGH    = (__half*)(W + o); o += 64 * (size_t)n;   // [n][128] fp16
    int*   binnedP  = (int*)AGGH;        // CSR-build scratch aliases AGGH
    int*   binnedN  = binnedP + Ep;
    __half* AGGH1   = AGGH;              // layer-1 agg rows [aggP|aggN]

    const int B = 256;
    const int aggBlocks = (2 * n + 31) / 32;
    const int mlpBlocks = (ngrp + 1) / 2;
    const int nbP = (Ep + 4095) / 4096, nbN = (En + 4095) / 4096;
    auto gcap = [](long t, int b) { long g = (t + b - 1) / b; return (int)(g < 2048 ? g : 2048); };

    // -------- scalars + pack + merged CSR build ------
    hipMemsetAsync(binCntP, 0, 2 * (size_t)nbin * sizeof(int), stream);
    pack_weights_kernel<<<1, 256, 0, stream>>>(W1b, W1u, W2b, W2u, a2b, a2u,
                                               WPK1, WPK2, A2PK);
    scalars1_kernel<<<512, B, 0, stream>>>(x, a1b, a1u, S, XH, XQ, XSP, XSN, n);
    bin_hist2_kernel<<<gcap((long)Ep + En, B), B, 0, stream>>>(pd, Ep, nd, En,
                                                               binCntP, binCntN, nbin);
    scan_bins2_kernel<<<2, 512, 0, stream>>>(binCntP, binCntN, nbin,
                                             binBaseP, binBaseN, gCurP, gCurN);
    bin_scatter2_kernel<<<nbP + nbN, 256, 0, stream>>>(
        ps, pd, Ep, binBaseP, gCurP, binnedP,
        ns, nd, En, binBaseN, gCurN, binnedN, nbin, nbP);
    bin_finalize2_kernel<<<2 * nbin, 256, 0, stream>>>(
        binnedP, binBaseP, rowptrP, esrcP,
        binnedN, binBaseN, rowptrN, esrcN, n, nbin);

    // ---------------- Layer 1 ----------------
    agg64_kernel<<<aggBlocks, 256, 0, stream>>>(
        rowptrP, esrcP, rowptrN, esrcN, S, XSP, XSN, XQ, AGGH1, n);
    mlp1f_kernel<<<mlpBlocks, 256, 0, stream>>>(AGGH1, XH, WPK1, A2PK,
                                                b1b, b1u, ZH, ZQ, S, SJP2, SJN2,
                                                n, ngrp);

    // ---------------- Layer 2 ----------------
    agg32pair_kernel<<<aggBlocks, 256, 0, stream>>>(
        rowptrP, esrcP, rowptrN, esrcN, S, SJP2, SJN2, ZQ, AGGH, n);
    mlp2_kernel<<<mlpBlocks, 256, 0, stream>>>(AGGH, ZH, WPK2, b2b, b2u, out, n, ngrp);
}

// Round 18
// 237.179 us; speedup vs baseline: 1.5221x; 1.1517x over previous
//
#include <hip/hip_runtime.h>
#include <hip/hip_fp16.h>
#include <math.h>

// ---------------------------------------------------------------------------
// SNEA pipeline (MFMA MLPs, int8 gathers, factored weights, 8-lane groups):
//   scalars1: layer-1 score projections; emits fp16 XH, int8 XQ, and packed
//             per-node weight tables XSP/XSN[src] = (e^sj, e^sj * rscl).
//   CSR build (merged dual-set): binned counting sort (bin=dst>>8), packed
//             recs src<<8|dl, rowptr2 = int2{start,end}. bin_hist runs on a
//             SMALL grid (304 blocks) so the per-block global-atomic flush
//             doesn't serialize on the 782 binCnt addresses.
//   agg64 / agg32pair: 8-LANE GROUP PER NODE (8 nodes/wave): lanes of a group
//             broadcast-load rec + weight pair, gather their 8B slice of the
//             64B int8 row, accumulate per-lane; den computed redundantly in
//             every lane -> NO cross-lane reductions, no shuffles at all.
//   mlp1f:   MFMA MLP -> tanh -> ZH fp16 + ZQ int8 + layer-2 si scores and
//             packed exp-sj tables SJP2/SJN2[src] = (e^sjL, e^sjH).
//   mlp2:    MFMA [16x96]@[96x32] -> tanh -> out.
// exp(si+sj) = exp(si)*exp(sj) exactly; no segment-max anywhere (scores
// ~N(0,1), unstabilized softmax is f32-safe and mathematically identical).
// ---------------------------------------------------------------------------

#define BIN_SHIFT 8
#define BIN_SPAN  256
#define NBIN_MAX  512          // n <= 131072; src fits 24 bits

typedef _Float16 half8 __attribute__((ext_vector_type(8)));
typedef float f32x4 __attribute__((ext_vector_type(4)));

// ----------------------------- CSR build ----------------------------------

__global__ __launch_bounds__(256) void bin_hist2_kernel(
        const int* __restrict__ dP, int Ep, const int* __restrict__ dN, int En,
        int* __restrict__ binCntP, int* __restrict__ binCntN, int nbin) {
    __shared__ int lcP[NBIN_MAX], lcN[NBIN_MAX];
    for (int i = threadIdx.x; i < nbin; i += 256) { lcP[i] = 0; lcN[i] = 0; }
    __syncthreads();
    int tot = Ep + En;
    for (int i = blockIdx.x * 256 + threadIdx.x; i < tot; i += gridDim.x * 256) {
        if (i < Ep) atomicAdd(&lcP[dP[i] >> BIN_SHIFT], 1);
        else        atomicAdd(&lcN[dN[i - Ep] >> BIN_SHIFT], 1);
    }
    __syncthreads();
    for (int b = threadIdx.x; b < nbin; b += 256) {
        if (lcP[b]) atomicAdd(&binCntP[b], lcP[b]);
        if (lcN[b]) atomicAdd(&binCntN[b], lcN[b]);
    }
}

// grid = 2 blocks x 512 threads: block 0 scans P, block 1 scans N.
__global__ __launch_bounds__(512) void scan_bins2_kernel(
        const int* __restrict__ binCntP, const int* __restrict__ binCntN, int nbin,
        int* __restrict__ binBaseP, int* __restrict__ binBaseN,
        int* __restrict__ gCurP, int* __restrict__ gCurN) {
    __shared__ int sd[512];
    const int* c  = blockIdx.x ? binCntN : binCntP;
    int* bb = blockIdx.x ? binBaseN : binBaseP;
    int* gc = blockIdx.x ? gCurN : gCurP;
    int tid = threadIdx.x;
    int v = (tid < nbin) ? c[tid] : 0;
    sd[tid] = v; __syncthreads();
    for (int off = 1; off < 512; off <<= 1) {
        int t = (tid >= off) ? sd[tid - off] : 0;
        __syncthreads();
        sd[tid] += t;
        __syncthreads();
    }
    if (tid < nbin) { bb[tid] = sd[tid] - v; gc[tid] = 0; }
    if (tid == nbin - 1) bb[nbin] = sd[tid];
}

__global__ __launch_bounds__(256) void bin_scatter2_kernel(
        const int* __restrict__ srcP, const int* __restrict__ dstP, int Ep,
        const int* __restrict__ binBaseP, int* __restrict__ gCurP, int* __restrict__ binnedP,
        const int* __restrict__ srcN, const int* __restrict__ dstN, int En,
        const int* __restrict__ binBaseN, int* __restrict__ gCurN, int* __restrict__ binnedN,
        int nbin, int nbP) {
    __shared__ int lc[NBIN_MAX];
    __shared__ int lbase[NBIN_MAX];
    bool second = blockIdx.x >= nbP;
    int blk = second ? blockIdx.x - nbP : blockIdx.x;
    const int* src = second ? srcN : srcP;
    const int* dst = second ? dstN : dstP;
    int E = second ? En : Ep;
    const int* binBase = second ? binBaseN : binBaseP;
    int* gCursor = second ? gCurN : gCurP;
    int* binned  = second ? binnedN : binnedP;

    for (int i = threadIdx.x; i < nbin; i += 256) lc[i] = 0;
    __syncthreads();
    int base0 = blk * 4096 + threadIdx.x * 16;
    int rank[16], bn[16];
    #pragma unroll
    for (int k = 0; k < 16; ++k) {
        int i = base0 + k;
        if (i < E) {
            int b = dst[i] >> BIN_SHIFT;
            bn[k] = b;
            rank[k] = atomicAdd(&lc[b], 1);
        }
    }
    __syncthreads();
    for (int b = threadIdx.x; b < nbin; b += 256)
        if (lc[b]) lbase[b] = atomicAdd(&gCursor[b], lc[b]);
    __syncthreads();
    #pragma unroll
    for (int k = 0; k < 16; ++k) {
        int i = base0 + k;
        if (i < E) {
            int b = bn[k];
            int pos = binBase[b] + lbase[b] + rank[k];
            binned[pos] = (src[i] << BIN_SHIFT) | (dst[i] & (BIN_SPAN - 1));
        }
    }
}

// grid = 2*nbin: pure CSR finalize: hist -> scan -> rowptr2 -> scatter rec.
__global__ __launch_bounds__(256) void bin_finalize2_kernel(
        const int* __restrict__ binnedP, const int* __restrict__ binBaseP,
        int2* __restrict__ rp2P, int* __restrict__ esP,
        const int* __restrict__ binnedN, const int* __restrict__ binBaseN,
        int2* __restrict__ rp2N, int* __restrict__ esN,
        int n, int nbin) {
    __shared__ int hist[BIN_SPAN];
    __shared__ int curs[BIN_SPAN];
    __shared__ int psum[256];
    int b = blockIdx.x;
    bool second = b >= nbin;
    if (second) b -= nbin;
    const int* binned  = second ? binnedN : binnedP;
    const int* binBase = second ? binBaseN : binBaseP;
    int2* rowptr2 = second ? rp2N : rp2P;
    int*  esrc    = second ? esN : esP;

    int tid = threadIdx.x;
    int lo = binBase[b], hi = binBase[b + 1];
    int nodeBase = b << BIN_SHIFT;
    hist[tid] = 0;
    __syncthreads();
    for (int i = lo + tid; i < hi; i += 256)
        atomicAdd(&hist[binned[i] & (BIN_SPAN - 1)], 1);
    __syncthreads();
    int a0 = hist[tid];
    psum[tid] = a0; __syncthreads();
    for (int off = 1; off < 256; off <<= 1) {
        int t = (tid >= off) ? psum[tid - off] : 0;
        __syncthreads();
        psum[tid] += t;
        __syncthreads();
    }
    int excl = psum[tid] - a0;
    curs[tid] = excl;
    {
        int node = nodeBase + tid;
        if (node < n) rowptr2[node] = make_int2(lo + excl, lo + excl + a0);
    }
    __syncthreads();
    for (int i = lo + tid; i < hi; i += 256) {
        int rec = binned[i];
        int slot = lo + atomicAdd(&curs[rec & (BIN_SPAN - 1)], 1);
        esrc[slot] = rec;      // keep packed
    }
}

// --------------------------- scalars (layer 1) ------------------------------

__global__ __launch_bounds__(256) void scalars1_kernel(
        const float* __restrict__ x,
        const float* __restrict__ a1b, const float* __restrict__ a1u,
        float* __restrict__ S, __half* __restrict__ xh,
        unsigned char* __restrict__ xq,
        float* __restrict__ XSP, float* __restrict__ XSN, int n) {
    __shared__ float sA[256];
    for (int k = threadIdx.x; k < 256; k += blockDim.x)
        sA[k] = (k < 128) ? a1b[k] : a1u[k - 128];
    __syncthreads();
    int grp = threadIdx.x >> 4, l = threadIdx.x & 15;
    for (int row = blockIdx.x * 16 + grp; row < n; row += gridDim.x * 16) {
        const float4 v = *(const float4*)(x + (size_t)row * 64 + l * 4);
        __half2 h0 = __floats2half2_rn(v.x, v.y);
        __half2 h1 = __floats2half2_rn(v.z, v.w);
        uint2 pk = make_uint2(*(unsigned*)&h0, *(unsigned*)&h1);
        *(uint2*)(xh + (size_t)row * 64 + l * 4) = pk;
        // per-row absmax -> scale s = rowmax/127; int8 biased copy
        float am = fmaxf(fmaxf(fabsf(v.x), fabsf(v.y)), fmaxf(fabsf(v.z), fabsf(v.w)));
        #pragma unroll
        for (int off = 1; off < 16; off <<= 1) am = fmaxf(am, __shfl_xor(am, off));
        am = fmaxf(am, 1e-8f);
        float inv = 127.f / am;
        int q0 = (int)rintf(v.x * inv) + 128;
        int q1 = (int)rintf(v.y * inv) + 128;
        int q2 = (int)rintf(v.z * inv) + 128;
        int q3 = (int)rintf(v.w * inv) + 128;
        unsigned qw = ((unsigned)q0 & 255u) | (((unsigned)q1 & 255u) << 8)
                    | (((unsigned)q2 & 255u) << 16) | (((unsigned)q3 & 255u) << 24);
        *(unsigned*)(xq + (size_t)row * 64 + l * 4) = qw;
        const float4 A0 = *(const float4*)(sA + l * 4);
        const float4 A1 = *(const float4*)(sA + 64 + l * 4);
        const float4 A2 = *(const float4*)(sA + 128 + l * 4);
        const float4 A3 = *(const float4*)(sA + 192 + l * 4);
        float p0 = fmaf(v.x, A0.x, fmaf(v.y, A0.y, fmaf(v.z, A0.z, v.w * A0.w)));
        float p1 = fmaf(v.x, A1.x, fmaf(v.y, A1.y, fmaf(v.z, A1.z, v.w * A1.w)));
        float p2 = fmaf(v.x, A2.x, fmaf(v.y, A2.y, fmaf(v.z, A2.z, v.w * A2.w)));
        float p3 = fmaf(v.x, A3.x, fmaf(v.y, A3.y, fmaf(v.z, A3.z, v.w * A3.w)));
        #pragma unroll
        for (int off = 1; off < 16; off <<= 1) {
            p0 += __shfl_xor(p0, off);
            p1 += __shfl_xor(p1, off);
            p2 += __shfl_xor(p2, off);
            p3 += __shfl_xor(p3, off);
        }
        if (l == 0) {
            float s = am * (1.0f / 127.f);
            S[row] = p0;                          // si pos
            S[2 * (size_t)n + row] = p2;          // si neg
            float e1 = __expf(p1);                // e^sj pos
            float e3 = __expf(p3);                // e^sj neg
            XSP[2 * (size_t)row]     = e1;
            XSP[2 * (size_t)row + 1] = e1 * s;
            XSN[2 * (size_t)row]     = e3;
            XSN[2 * (size_t)row + 1] = e3 * s;
        }
    }
}

// -------- layer 1 aggregation (8-lane group per node, no reductions) -------

__global__ __launch_bounds__(256) void agg64_kernel(
        const int2* __restrict__ rpA, const int* __restrict__ esA,
        const int2* __restrict__ rpB, const int* __restrict__ esB,
        const float* __restrict__ S,
        const float* __restrict__ XSP, const float* __restrict__ XSN,
        const unsigned char* __restrict__ xq, __half* __restrict__ AGGH1, int n) {
    int gid = blockIdx.x * 32 + (threadIdx.x >> 3);
    int L = threadIdx.x & 7;
    if (gid >= 2 * n) return;
    bool second = gid >= n;
    int node = second ? gid - n : gid;
    const int2*  rp = second ? rpB : rpA;
    const int*   es = second ? esB : esA;
    const float* si = S + (second ? 2 : 0) * (size_t)n;
    const float* xs = second ? XSN : XSP;
    float esi = __expf(si[node]);

    int2 se = rp[node];
    int start = se.x, len = se.y - se.x;
    float a0=0,a1=0,a2=0,a3=0,a4=0,a5=0,a6=0,a7=0;
    float den = 0.f, sden = 0.f;

    int e = 0;
    for (; e + 2 <= len; e += 2) {
        int rec0 = es[start + e];
        int rec1 = es[start + e + 1];
        int src0 = (int)((unsigned)rec0 >> BIN_SHIFT);
        int src1 = (int)((unsigned)rec1 >> BIN_SHIFT);
        float2 x20 = *(const float2*)(xs + 2 * (size_t)src0);
        float2 x21 = *(const float2*)(xs + 2 * (size_t)src1);
        uint2 pk0 = *(const uint2*)(xq + (size_t)src0 * 64 + L * 8);
        uint2 pk1 = *(const uint2*)(xq + (size_t)src1 * 64 + L * 8);
        float ws0 = esi * x20.y;
        float ws1 = esi * x21.y;
        den  += esi * x20.x + esi * x21.x;
        sden += ws0 + ws1;
        a0 = fmaf(ws0, (float)( pk0.x        & 0xffu), a0);
        a1 = fmaf(ws0, (float)((pk0.x >> 8 ) & 0xffu), a1);
        a2 = fmaf(ws0, (float)((pk0.x >> 16) & 0xffu), a2);
        a3 = fmaf(ws0, (float)( pk0.x >> 24        ), a3);
        a4 = fmaf(ws0, (float)( pk0.y        & 0xffu), a4);
        a5 = fmaf(ws0, (float)((pk0.y >> 8 ) & 0xffu), a5);
        a6 = fmaf(ws0, (float)((pk0.y >> 16) & 0xffu), a6);
        a7 = fmaf(ws0, (float)( pk0.y >> 24        ), a7);
        a0 = fmaf(ws1, (float)( pk1.x        & 0xffu), a0);
        a1 = fmaf(ws1, (float)((pk1.x >> 8 ) & 0xffu), a1);
        a2 = fmaf(ws1, (float)((pk1.x >> 16) & 0xffu), a2);
        a3 = fmaf(ws1, (float)( pk1.x >> 24        ), a3);
        a4 = fmaf(ws1, (float)( pk1.y        & 0xffu), a4);
        a5 = fmaf(ws1, (float)((pk1.y >> 8 ) & 0xffu), a5);
        a6 = fmaf(ws1, (float)((pk1.y >> 16) & 0xffu), a6);
        a7 = fmaf(ws1, (float)( pk1.y >> 24        ), a7);
    }
    if (e < len) {
        int rec0 = es[start + e];
        int src0 = (int)((unsigned)rec0 >> BIN_SHIFT);
        float2 x20 = *(const float2*)(xs + 2 * (size_t)src0);
        uint2 pk0 = *(const uint2*)(xq + (size_t)src0 * 64 + L * 8);
        float ws0 = esi * x20.y;
        den  += esi * x20.x;
        sden += ws0;
        a0 = fmaf(ws0, (float)( pk0.x        & 0xffu), a0);
        a1 = fmaf(ws0, (float)((pk0.x >> 8 ) & 0xffu), a1);
        a2 = fmaf(ws0, (float)((pk0.x >> 16) & 0xffu), a2);
        a3 = fmaf(ws0, (float)( pk0.x >> 24        ), a3);
        a4 = fmaf(ws0, (float)( pk0.y        & 0xffu), a4);
        a5 = fmaf(ws0, (float)((pk0.y >> 8 ) & 0xffu), a5);
        a6 = fmaf(ws0, (float)((pk0.y >> 16) & 0xffu), a6);
        a7 = fmaf(ws0, (float)( pk0.y >> 24        ), a7);
    }
    float r = 1.0f / fmaxf(den, 1e-16f);
    float bd = 128.f * sden;
    __half2 p0 = __floats2half2_rn((a0 - bd) * r, (a1 - bd) * r);
    __half2 p1 = __floats2half2_rn((a2 - bd) * r, (a3 - bd) * r);
    __half2 p2 = __floats2half2_rn((a4 - bd) * r, (a5 - bd) * r);
    __half2 p3 = __floats2half2_rn((a6 - bd) * r, (a7 - bd) * r);
    uint4 pk = make_uint4(*(unsigned*)&p0, *(unsigned*)&p1, *(unsigned*)&p2, *(unsigned*)&p3);
    *(uint4*)(AGGH1 + (size_t)node * 128 + (second ? 64 : 0) + L * 8) = pk;
}

// --------------------- weight packing for MFMA MLPs ------------------------

__global__ __launch_bounds__(256) void pack_weights_kernel(
        const float* __restrict__ W1b, const float* __restrict__ W1u,
        const float* __restrict__ W2b, const float* __restrict__ W2u,
        const float* __restrict__ a2b, const float* __restrict__ a2u,
        __half* __restrict__ WPK1, __half* __restrict__ WPK2,
        __half* __restrict__ A2PK) {
    int t = threadIdx.x;
    for (int i = t; i < 8192; i += 256) {
        int j = i & 7, lane = (i >> 3) & 63, ct = (i >> 9) & 1, kk = (i >> 10) & 3, fam = i >> 12;
        const float* Wx = fam ? W1u : W1b;
        int k = kk * 32 + ((lane >> 4) << 3) + j;
        int col = ct * 16 + (lane & 15);
        WPK1[i] = __float2half(Wx[k * 32 + col]);
    }
    for (int i = t; i < 6144; i += 256) {
        int j = i & 7, lane = (i >> 3) & 63, ct = (i >> 9) & 1;
        int rest = i >> 10;                 // (fam*3 + kk)
        int kk = rest % 3, fam = rest / 3;
        const float* Wx = fam ? W2u : W2b;
        int k = kk * 32 + ((lane >> 4) << 3) + j;
        int col = ct * 16 + (lane & 15);
        WPK2[i] = __float2half(Wx[k * 32 + col]);
    }
    for (int i = t; i < 512; i += 256) {
        int j = i & 7, lane = i >> 3;
        int q = lane & 15, k = ((lane >> 4) << 3) + j;
        float v = 0.f;
        if (q == 0) v = a2b[k];
        else if (q == 1) v = a2b[32 + k];
        else if (q == 2) v = a2u[k];
        else if (q == 3) v = a2u[32 + k];
        A2PK[i] = __float2half(v);
    }
}

// ---------------- layer 1 MLP (MFMA) + tanh + layer-2 scores ---------------

#define ZPITCH 40   // halves; 80B rows keep uint4/half8 accesses 16B-aligned

__global__ __launch_bounds__(256) void mlp1f_kernel(
        const __half* __restrict__ AGGH1, const __half* __restrict__ xh,
        const __half* __restrict__ WPK1, const __half* __restrict__ A2PK,
        const float* __restrict__ b1b, const float* __restrict__ b1u,
        __half* __restrict__ zh, unsigned char* __restrict__ zq,
        float* __restrict__ S, float* __restrict__ SJP2, float* __restrict__ SJN2,
        int n, int ngrp) {
    __shared__ __half zLds[4][16][ZPITCH];
    int w = threadIdx.x >> 6, lane = threadIdx.x & 63;
    int fam = w & 1, l15 = lane & 15, lq = lane >> 4;

    half8 bfrag[4][2];
    #pragma unroll
    for (int kk = 0; kk < 4; ++kk)
        #pragma unroll
        for (int ct = 0; ct < 2; ++ct)
            bfrag[kk][ct] = *(const half8*)(WPK1 + (((fam * 4 + kk) * 2 + ct) << 9) + lane * 8);
    half8 a2frag = *(const half8*)(A2PK + lane * 8);
    const float* bb = fam ? b1u : b1b;
    float bias0 = bb[l15], bias1 = bb[16 + l15];

    int grp = blockIdx.x * 2 + (w >> 1);
    if (grp >= ngrp) return;
    int gbase = grp * 16;
    int arow = gbase + l15; if (arow >= n) arow = n - 1;
    const __half* aggRow = AGGH1 + (size_t)arow * 128 + fam * 64;
    const __half* xRow   = xh   + (size_t)arow * 64;

    f32x4 acc0 = {0.f, 0.f, 0.f, 0.f}, acc1 = {0.f, 0.f, 0.f, 0.f};
    #pragma unroll
    for (int kk = 0; kk < 2; ++kk) {
        half8 a = *(const half8*)(aggRow + kk * 32 + lq * 8);
        acc0 = __builtin_amdgcn_mfma_f32_16x16x32_f16(a, bfrag[kk][0], acc0, 0, 0, 0);
        acc1 = __builtin_amdgcn_mfma_f32_16x16x32_f16(a, bfrag[kk][1], acc1, 0, 0, 0);
    }
    #pragma unroll
    for (int kk = 2; kk < 4; ++kk) {
        half8 a = *(const half8*)(xRow + (kk - 2) * 32 + lq * 8);
        acc0 = __builtin_amdgcn_mfma_f32_16x16x32_f16(a, bfrag[kk][0], acc0, 0, 0, 0);
        acc1 = __builtin_amdgcn_mfma_f32_16x16x32_f16(a, bfrag[kk][1], acc1, 0, 0, 0);
    }
    #pragma unroll
    for (int r = 0; r < 4; ++r) {
        int row = lq * 4 + r;
        zLds[w][row][l15]      = __float2half(tanhf(acc0[r] + bias0));
        zLds[w][row][16 + l15] = __float2half(tanhf(acc1[r] + bias1));
    }
    {
        int node = lane >> 2, chunk = lane & 3;
        int gn = gbase + node;
        uint4 v = *(const uint4*)(&zLds[w][node][chunk * 8]);
        if (gn < n) *(uint4*)(zh + (size_t)gn * 64 + fam * 32 + chunk * 8) = v;
        // int8 copy: biased uint8 q = round(z*127)+128 (z in (-1,1) from tanh)
        const __half* zp = &zLds[w][node][chunk * 8];
        unsigned lo = 0, hi = 0;
        #pragma unroll
        for (int k = 0; k < 4; ++k) {
            int q = (int)rintf(__half2float(zp[k]) * 127.f) + 128;
            lo |= ((unsigned)q & 255u) << (8 * k);
        }
        #pragma unroll
        for (int k = 0; k < 4; ++k) {
            int q = (int)rintf(__half2float(zp[4 + k]) * 127.f) + 128;
            hi |= ((unsigned)q & 255u) << (8 * k);
        }
        if (gn < n) *(uint2*)(zq + (size_t)gn * 64 + fam * 32 + chunk * 8) = make_uint2(lo, hi);
    }
    {
        half8 a = *(const half8*)(&zLds[w][l15][lq * 8]);
        f32x4 sacc = {0.f, 0.f, 0.f, 0.f};
        sacc = __builtin_amdgcn_mfma_f32_16x16x32_f16(a, a2frag, sacc, 0, 0, 0);
        // fam0 (zb): q0->S0(si bp), q1->e^sj bp -> SJP2.x, q2->S6(si un),
        //            q3->e^sj un -> SJN2.x
        // fam1 (zu): q0->S2(si bn), q1->e^sj bn -> SJN2.y, q2->S4(si up),
        //            q3->e^sj up -> SJP2.y
        if (l15 < 4) {
            #pragma unroll
            for (int r = 0; r < 4; ++r) {
                int node = gbase + lq * 4 + r;
                if (node >= n) continue;
                float v = sacc[r];
                if (fam == 0) {
                    if (l15 == 0)      S[node] = v;
                    else if (l15 == 1) SJP2[2 * (size_t)node]     = __expf(v);
                    else if (l15 == 2) S[6 * (size_t)n + node] = v;
                    else               SJN2[2 * (size_t)node]     = __expf(v);
                } else {
                    if (l15 == 0)      S[2 * (size_t)n + node] = v;
                    else if (l15 == 1) SJN2[2 * (size_t)node + 1] = __expf(v);
                    else if (l15 == 2) S[4 * (size_t)n + node] = v;
                    else               SJP2[2 * (size_t)node + 1] = __expf(v);
                }
            }
        }
    }
}

// ------- layer 2 aggregation (8-lane group per node, no reductions) --------

// AGGH row layout per node: [bp(32) | bn(32) | up(32) | un(32)] fp16.
// Lane L<4 accumulates L family (bytes L*8 of zq = zb cols), L>=4 H family.
__global__ __launch_bounds__(256) void agg32pair_kernel(
        const int2* __restrict__ rpA, const int* __restrict__ esA,
        const int2* __restrict__ rpB, const int* __restrict__ esB,
        const float* __restrict__ S,
        const float* __restrict__ SJP2, const float* __restrict__ SJN2,
        const unsigned char* __restrict__ zq, __half* __restrict__ AGGH, int n) {
    int gid = blockIdx.x * 32 + (threadIdx.x >> 3);
    int L = threadIdx.x & 7;
    if (gid >= 2 * n) return;
    bool second = gid >= n;
    int node = second ? gid - n : gid;
    const int2* rp = second ? rpB : rpA;
    const int*  es = second ? esB : esA;
    // pos: L=bp(si S0) H=up(si S4).  neg: L=un(si S6) H=bn(si S2).
    const float* siL = S + (second ? 6 : 0) * (size_t)n;
    const float* siH = S + (second ? 2 : 4) * (size_t)n;
    const float* sj2 = second ? SJN2 : SJP2;
    float esiL = __expf(siL[node]), esiH = __expf(siH[node]);
    bool lowf = L < 4;
    float esiF = lowf ? esiL : esiH;

    int2 se = rp[node];
    int start = se.x, len = se.y - se.x;
    float a0=0,a1=0,a2=0,a3=0,a4=0,a5=0,a6=0,a7=0;
    float denL = 0.f, denH = 0.f;

    int e = 0;
    for (; e + 2 <= len; e += 2) {
        int rec0 = es[start + e];
        int rec1 = es[start + e + 1];
        int src0 = (int)((unsigned)rec0 >> BIN_SHIFT);
        int src1 = (int)((unsigned)rec1 >> BIN_SHIFT);
        float2 e20 = *(const float2*)(sj2 + 2 * (size_t)src0);
        float2 e21 = *(const float2*)(sj2 + 2 * (size_t)src1);
        uint2 pk0 = *(const uint2*)(zq + (size_t)src0 * 64 + L * 8);
        uint2 pk1 = *(const uint2*)(zq + (size_t)src1 * 64 + L * 8);
        denL += esiL * e20.x + esiL * e21.x;
        denH += esiH * e20.y + esiH * e21.y;
        float wt0 = esiF * (lowf ? e20.x : e20.y);
        float wt1 = esiF * (lowf ? e21.x : e21.y);
        a0 = fmaf(wt0, (float)( pk0.x        & 0xffu), a0);
        a1 = fmaf(wt0, (float)((pk0.x >> 8 ) & 0xffu), a1);
        a2 = fmaf(wt0, (float)((pk0.x >> 16) & 0xffu), a2);
        a3 = fmaf(wt0, (float)( pk0.x >> 24        ), a3);
        a4 = fmaf(wt0, (float)( pk0.y        & 0xffu), a4);
        a5 = fmaf(wt0, (float)((pk0.y >> 8 ) & 0xffu), a5);
        a6 = fmaf(wt0, (float)((pk0.y >> 16) & 0xffu), a6);
        a7 = fmaf(wt0, (float)( pk0.y >> 24        ), a7);
        a0 = fmaf(wt1, (float)( pk1.x        & 0xffu), a0);
        a1 = fmaf(wt1, (float)((pk1.x >> 8 ) & 0xffu), a1);
        a2 = fmaf(wt1, (float)((pk1.x >> 16) & 0xffu), a2);
        a3 = fmaf(wt1, (float)( pk1.x >> 24        ), a3);
        a4 = fmaf(wt1, (float)( pk1.y        & 0xffu), a4);
        a5 = fmaf(wt1, (float)((pk1.y >> 8 ) & 0xffu), a5);
        a6 = fmaf(wt1, (float)((pk1.y >> 16) & 0xffu), a6);
        a7 = fmaf(wt1, (float)( pk1.y >> 24        ), a7);
    }
    if (e < len) {
        int rec0 = es[start + e];
        int src0 = (int)((unsigned)rec0 >> BIN_SHIFT);
        float2 e20 = *(const float2*)(sj2 + 2 * (size_t)src0);
        uint2 pk0 = *(const uint2*)(zq + (size_t)src0 * 64 + L * 8);
        denL += esiL * e20.x;
        denH += esiH * e20.y;
        float wt0 = esiF * (lowf ? e20.x : e20.y);
        a0 = fmaf(wt0, (float)( pk0.x        & 0xffu), a0);
        a1 = fmaf(wt0, (float)((pk0.x >> 8 ) & 0xffu), a1);
        a2 = fmaf(wt0, (float)((pk0.x >> 16) & 0xffu), a2);
        a3 = fmaf(wt0, (float)( pk0.x >> 24        ), a3);
        a4 = fmaf(wt0, (float)( pk0.y        & 0xffu), a4);
        a5 = fmaf(wt0, (float)((pk0.y >> 8 ) & 0xffu), a5);
        a6 = fmaf(wt0, (float)((pk0.y >> 16) & 0xffu), a6);
        a7 = fmaf(wt0, (float)( pk0.y >> 24        ), a7);
    }
    float d = lowf ? denL : denH;
    float r = (d > 0.f) ? (1.0f / d) : 0.f;
    const float c = 1.0f / 127.0f;
    float bd = 128.f * d;
    float o0 = (a0 - bd) * r * c, o1 = (a1 - bd) * r * c;
    float o2 = (a2 - bd) * r * c, o3 = (a3 - bd) * r * c;
    float o4 = (a4 - bd) * r * c, o5 = (a5 - bd) * r * c;
    float o6 = (a6 - bd) * r * c, o7 = (a7 - bd) * r * c;
    __half2 p0 = __floats2half2_rn(o0, o1);
    __half2 p1 = __floats2half2_rn(o2, o3);
    __half2 p2 = __floats2half2_rn(o4, o5);
    __half2 p3 = __floats2half2_rn(o6, o7);
    uint4 pk = make_uint4(*(unsigned*)&p0, *(unsigned*)&p1, *(unsigned*)&p2, *(unsigned*)&p3);
    // pos: L=bp->0, H=up->64 ; neg: L=un->96, H=bn->32
    int base = second ? (lowf ? 96 : 32) : (lowf ? 0 : 64);
    *(uint4*)(AGGH + (size_t)node * 128 + base + (L & 3) * 8) = pk;
}

// ------------------------------ MLP 2 (MFMA) -------------------------------

__global__ __launch_bounds__(256) void mlp2_kernel(
        const __half* __restrict__ AGGH, const __half* __restrict__ zh,
        const __half* __restrict__ WPK2,
        const float* __restrict__ b2b, const float* __restrict__ b2u,
        float* __restrict__ out, int n, int ngrp) {
    int w = threadIdx.x >> 6, lane = threadIdx.x & 63;
    int fam = w & 1, l15 = lane & 15, lq = lane >> 4;

    half8 bfrag[3][2];
    #pragma unroll
    for (int kk = 0; kk < 3; ++kk)
        #pragma unroll
        for (int ct = 0; ct < 2; ++ct)
            bfrag[kk][ct] = *(const half8*)(WPK2 + (((fam * 3 + kk) * 2 + ct) << 9) + lane * 8);
    const float* bb = fam ? b2u : b2b;
    float bias0 = bb[l15], bias1 = bb[16 + l15];

    int grp = blockIdx.x * 2 + (w >> 1);
    if (grp >= ngrp) return;
    int gbase = grp * 16;
    int arow = gbase + l15; if (arow >= n) arow = n - 1;
    const __half* aggRow = AGGH + (size_t)arow * 128 + fam * 64;
    const __half* zRow   = zh   + (size_t)arow * 64 + fam * 32;

    f32x4 acc0 = {0.f, 0.f, 0.f, 0.f}, acc1 = {0.f, 0.f, 0.f, 0.f};
    #pragma unroll
    for (int kk = 0; kk < 2; ++kk) {
        half8 a = *(const half8*)(aggRow + kk * 32 + lq * 8);
        acc0 = __builtin_amdgcn_mfma_f32_16x16x32_f16(a, bfrag[kk][0], acc0, 0, 0, 0);
        acc1 = __builtin_amdgcn_mfma_f32_16x16x32_f16(a, bfrag[kk][1], acc1, 0, 0, 0);
    }
    {
        half8 a = *(const half8*)(zRow + lq * 8);
        acc0 = __builtin_amdgcn_mfma_f32_16x16x32_f16(a, bfrag[2][0], acc0, 0, 0, 0);
        acc1 = __builtin_amdgcn_mfma_f32_16x16x32_f16(a, bfrag[2][1], acc1, 0, 0, 0);
    }
    #pragma unroll
    for (int r = 0; r < 4; ++r) {
        int node = gbase + lq * 4 + r;
        if (node < n) {
            out[(size_t)node * 64 + fam * 32 + l15]      = tanhf(acc0[r] + bias0);
            out[(size_t)node * 64 + fam * 32 + 16 + l15] = tanhf(acc1[r] + bias1);
        }
    }
}

// ------------------------------ launcher -----------------------------------

extern "C" void kernel_launch(void* const* d_in, const int* in_sizes, int n_in,
                              void* d_out, int out_size, void* d_ws, size_t ws_size,
                              hipStream_t stream) {
    const float* x   = (const float*)d_in[0];
    const int*   pos = (const int*)d_in[1];
    const int*   neg = (const int*)d_in[2];
    const float* a1b = (const float*)d_in[3];
    const float* a1u = (const float*)d_in[4];
    const float* W1b = (const float*)d_in[5];
    const float* b1b = (const float*)d_in[6];
    const float* W1u = (const float*)d_in[7];
    const float* b1u = (const float*)d_in[8];
    const float* a2b = (const float*)d_in[9];
    const float* a2u = (const float*)d_in[10];
    const float* W2b = (const float*)d_in[11];
    const float* b2b = (const float*)d_in[12];
    const float* W2u = (const float*)d_in[13];
    const float* b2u = (const float*)d_in[14];
    float* out = (float*)d_out;

    const int n  = in_sizes[0] / 64;
    const int Ep = in_sizes[1] / 2;
    const int En = in_sizes[2] / 2;
    const int* ps = pos;  const int* pd = pos + Ep;
    const int* ns = neg;  const int* nd = neg + En;
    const int nbin = (n + BIN_SPAN - 1) >> BIN_SHIFT;   // 391 for n=100000
    const int ngrp = (n + 15) / 16;

    // ws layout (4-byte words)
    unsigned* W = (unsigned*)d_ws;
    size_t o = 0;
    float* S        = (float*)(W + o); o += 8 * (size_t)n;
    int2*  rowptrP  = (int2*)(W + o);  o += 2 * (size_t)n;
    int2*  rowptrN  = (int2*)(W + o);  o += 2 * (size_t)n;
    int*   binCntP  = (int*)(W + o);   o += nbin;
    int*   binCntN  = (int*)(W + o);   o += nbin;
    int*   binBaseP = (int*)(W + o);   o += nbin + 1;
    int*   binBaseN = (int*)(W + o);   o += nbin + 1;
    int*   gCurP    = (int*)(W + o);   o += nbin;
    int*   gCurN    = (int*)(W + o);   o += nbin;
    int*   esrcP    = (int*)(W + o);   o += Ep;
    int*   esrcN    = (int*)(W + o);   o += En;
    o = (o + 1) & ~(size_t)1;
    float* XSP      = (float*)(W + o); o += 2 * (size_t)n;   // (e^sj, e^sj*rscl) pos
    float* XSN      = (float*)(W + o); o += 2 * (size_t)n;   // (e^sj, e^sj*rscl) neg
    float* SJP2     = (float*)(W + o); o += 2 * (size_t)n;   // (e^sjL, e^sjH) pos
    float* SJN2     = (float*)(W + o); o += 2 * (size_t)n;   // (e^sjL, e^sjH) neg
    o = (o + 3) & ~(size_t)3;
    __half* XH      = (__half*)(W + o); o += 32 * (size_t)n;   // x rows fp16
    __half* ZH      = (__half*)(W + o); o += 32 * (size_t)n;   // z rows fp16
    unsigned char* XQ = (unsigned char*)(W + o); o += 16 * (size_t)n; // x rows u8
    unsigned char* ZQ = (unsigned char*)(W + o); o += 16 * (size_t)n; // z rows u8
    o = (o + 3) & ~(size_t)3;
    __half* WPK1    = (__half*)(W + o); o += 4096;
    __half* WPK2    = (__half*)(W + o); o += 3072;
    __half* A2PK    = (__half*)(W + o); o += 256;
    o = (o + 3) & ~(size_t)3;
    __half* AGGH    = (__half*)(W + o); o += 64 * (size_t)n;   // [n][128] fp16
    int*   binnedP  = (int*)AGGH;        // CSR-build scratch aliases AGGH
    int*   binnedN  = binnedP + Ep;
    __half* AGGH1   = AGGH;              // layer-1 agg rows [aggP|aggN]

    const int B = 256;
    const int aggBlocks = (2 * n + 31) / 32;
    const int mlpBlocks = (ngrp + 1) / 2;
    const int nbP = (Ep + 4095) / 4096, nbN = (En + 4095) / 4096;

    // -------- scalars + pack + merged CSR build ------
    hipMemsetAsync(binCntP, 0, 2 * (size_t)nbin * sizeof(int), stream);
    pack_weights_kernel<<<1, 256, 0, stream>>>(W1b, W1u, W2b, W2u, a2b, a2u,
                                               WPK1, WPK2, A2PK);
    scalars1_kernel<<<512, B, 0, stream>>>(x, a1b, a1u, S, XH, XQ, XSP, XSN, n);
    // SMALL grid: per-block flush does ~782 global atomics; 304 blocks keeps
    // same-address serialization ~7x lower than a 2048-block launch.
    bin_hist2_kernel<<<304, B, 0, stream>>>(pd, Ep, nd, En, binCntP, binCntN, nbin);
    scan_bins2_kernel<<<2, 512, 0, stream>>>(binCntP, binCntN, nbin,
                                             binBaseP, binBaseN, gCurP, gCurN);
    bin_scatter2_kernel<<<nbP + nbN, 256, 0, stream>>>(
        ps, pd, Ep, binBaseP, gCurP, binnedP,
        ns, nd, En, binBaseN, gCurN, binnedN, nbin, nbP);
    bin_finalize2_kernel<<<2 * nbin, 256, 0, stream>>>(
        binnedP, binBaseP, rowptrP, esrcP,
        binnedN, binBaseN, rowptrN, esrcN, n, nbin);

    // ---------------- Layer 1 ----------------
    agg64_kernel<<<aggBlocks, 256, 0, stream>>>(
        rowptrP, esrcP, rowptrN, esrcN, S, XSP, XSN, XQ, AGGH1, n);
    mlp1f_kernel<<<mlpBlocks, 256, 0, stream>>>(AGGH1, XH, WPK1, A2PK,
                                                b1b, b1u, ZH, ZQ, S, SJP2, SJN2,
                                                n, ngrp);

    // ---------------- Layer 2 ----------------
    agg32pair_kernel<<<aggBlocks, 256, 0, stream>>>(
        rowptrP, esrcP, rowptrN, esrcN, S, SJP2, SJN2, ZQ, AGGH, n);
    mlp2_kernel<<<mlpBlocks, 256, 0, stream>>>(AGGH, ZH, WPK2, b2b, b2u, out, n, ngrp);
}

// Round 19
// 234.232 us; speedup vs baseline: 1.5413x; 1.0126x over previous
//
#include <hip/hip_runtime.h>
#include <hip/hip_fp16.h>
#include <math.h>

// ---------------------------------------------------------------------------
// SNEA pipeline (MFMA MLPs, int8 gathers, factored weights, 8-lane groups):
//   scalars1: layer-1 score projections; emits fp16 XH, int8 XQ, and packed
//             per-node weight tables XSP/XSN[src] = (e^sj, e^sj * rscl).
//   CSR build (merged dual-set): binned counting sort (bin=dst>>8), packed
//             recs src<<8|dl, rowptr2 = int2{start,end}. bin_hist on a small
//             grid (304 blocks) so the global-atomic flush doesn't serialize.
//   agg64 / agg32pair: 8-LANE GROUP PER NODE, 4 EDGES IN FLIGHT: lanes of a
//             group broadcast-load 4 recs + weight pairs + their 8B payload
//             slices before any fma chain; den computed redundantly in every
//             lane -> no cross-lane reductions, no shuffles at all.
//   mlp1f:   MFMA MLP -> tanh -> ZH fp16 + ZQ int8 + layer-2 si scores and
//             packed exp-sj tables SJP2/SJN2[src] = (e^sjL, e^sjH).
//   mlp2:    MFMA [16x96]@[96x32] -> tanh -> out.
// exp(si+sj) = exp(si)*exp(sj) exactly; no segment-max anywhere (scores
// ~N(0,1), unstabilized softmax is f32-safe and mathematically identical).
// ---------------------------------------------------------------------------

#define BIN_SHIFT 8
#define BIN_SPAN  256
#define NBIN_MAX  512          // n <= 131072; src fits 24 bits

typedef _Float16 half8 __attribute__((ext_vector_type(8)));
typedef float f32x4 __attribute__((ext_vector_type(4)));

// ----------------------------- CSR build ----------------------------------

__global__ __launch_bounds__(256) void bin_hist2_kernel(
        const int* __restrict__ dP, int Ep, const int* __restrict__ dN, int En,
        int* __restrict__ binCntP, int* __restrict__ binCntN, int nbin) {
    __shared__ int lcP[NBIN_MAX], lcN[NBIN_MAX];
    for (int i = threadIdx.x; i < nbin; i += 256) { lcP[i] = 0; lcN[i] = 0; }
    __syncthreads();
    int tot = Ep + En;
    for (int i = blockIdx.x * 256 + threadIdx.x; i < tot; i += gridDim.x * 256) {
        if (i < Ep) atomicAdd(&lcP[dP[i] >> BIN_SHIFT], 1);
        else        atomicAdd(&lcN[dN[i - Ep] >> BIN_SHIFT], 1);
    }
    __syncthreads();
    for (int b = threadIdx.x; b < nbin; b += 256) {
        if (lcP[b]) atomicAdd(&binCntP[b], lcP[b]);
        if (lcN[b]) atomicAdd(&binCntN[b], lcN[b]);
    }
}

// grid = 2 blocks x 512 threads: block 0 scans P, block 1 scans N.
__global__ __launch_bounds__(512) void scan_bins2_kernel(
        const int* __restrict__ binCntP, const int* __restrict__ binCntN, int nbin,
        int* __restrict__ binBaseP, int* __restrict__ binBaseN,
        int* __restrict__ gCurP, int* __restrict__ gCurN) {
    __shared__ int sd[512];
    const int* c  = blockIdx.x ? binCntN : binCntP;
    int* bb = blockIdx.x ? binBaseN : binBaseP;
    int* gc = blockIdx.x ? gCurN : gCurP;
    int tid = threadIdx.x;
    int v = (tid < nbin) ? c[tid] : 0;
    sd[tid] = v; __syncthreads();
    for (int off = 1; off < 512; off <<= 1) {
        int t = (tid >= off) ? sd[tid - off] : 0;
        __syncthreads();
        sd[tid] += t;
        __syncthreads();
    }
    if (tid < nbin) { bb[tid] = sd[tid] - v; gc[tid] = 0; }
    if (tid == nbin - 1) bb[nbin] = sd[tid];
}

__global__ __launch_bounds__(256) void bin_scatter2_kernel(
        const int* __restrict__ srcP, const int* __restrict__ dstP, int Ep,
        const int* __restrict__ binBaseP, int* __restrict__ gCurP, int* __restrict__ binnedP,
        const int* __restrict__ srcN, const int* __restrict__ dstN, int En,
        const int* __restrict__ binBaseN, int* __restrict__ gCurN, int* __restrict__ binnedN,
        int nbin, int nbP) {
    __shared__ int lc[NBIN_MAX];
    __shared__ int lbase[NBIN_MAX];
    bool second = blockIdx.x >= nbP;
    int blk = second ? blockIdx.x - nbP : blockIdx.x;
    const int* src = second ? srcN : srcP;
    const int* dst = second ? dstN : dstP;
    int E = second ? En : Ep;
    const int* binBase = second ? binBaseN : binBaseP;
    int* gCursor = second ? gCurN : gCurP;
    int* binned  = second ? binnedN : binnedP;

    for (int i = threadIdx.x; i < nbin; i += 256) lc[i] = 0;
    __syncthreads();
    int base0 = blk * 4096 + threadIdx.x * 16;
    int rank[16], bn[16];
    #pragma unroll
    for (int k = 0; k < 16; ++k) {
        int i = base0 + k;
        if (i < E) {
            int b = dst[i] >> BIN_SHIFT;
            bn[k] = b;
            rank[k] = atomicAdd(&lc[b], 1);
        }
    }
    __syncthreads();
    for (int b = threadIdx.x; b < nbin; b += 256)
        if (lc[b]) lbase[b] = atomicAdd(&gCursor[b], lc[b]);
    __syncthreads();
    #pragma unroll
    for (int k = 0; k < 16; ++k) {
        int i = base0 + k;
        if (i < E) {
            int b = bn[k];
            int pos = binBase[b] + lbase[b] + rank[k];
            binned[pos] = (src[i] << BIN_SHIFT) | (dst[i] & (BIN_SPAN - 1));
        }
    }
}

// grid = 2*nbin: pure CSR finalize: hist -> scan -> rowptr2 -> scatter rec.
__global__ __launch_bounds__(256) void bin_finalize2_kernel(
        const int* __restrict__ binnedP, const int* __restrict__ binBaseP,
        int2* __restrict__ rp2P, int* __restrict__ esP,
        const int* __restrict__ binnedN, const int* __restrict__ binBaseN,
        int2* __restrict__ rp2N, int* __restrict__ esN,
        int n, int nbin) {
    __shared__ int hist[BIN_SPAN];
    __shared__ int curs[BIN_SPAN];
    __shared__ int psum[256];
    int b = blockIdx.x;
    bool second = b >= nbin;
    if (second) b -= nbin;
    const int* binned  = second ? binnedN : binnedP;
    const int* binBase = second ? binBaseN : binBaseP;
    int2* rowptr2 = second ? rp2N : rp2P;
    int*  esrc    = second ? esN : esP;

    int tid = threadIdx.x;
    int lo = binBase[b], hi = binBase[b + 1];
    int nodeBase = b << BIN_SHIFT;
    hist[tid] = 0;
    __syncthreads();
    for (int i = lo + tid; i < hi; i += 256)
        atomicAdd(&hist[binned[i] & (BIN_SPAN - 1)], 1);
    __syncthreads();
    int a0 = hist[tid];
    psum[tid] = a0; __syncthreads();
    for (int off = 1; off < 256; off <<= 1) {
        int t = (tid >= off) ? psum[tid - off] : 0;
        __syncthreads();
        psum[tid] += t;
        __syncthreads();
    }
    int excl = psum[tid] - a0;
    curs[tid] = excl;
    {
        int node = nodeBase + tid;
        if (node < n) rowptr2[node] = make_int2(lo + excl, lo + excl + a0);
    }
    __syncthreads();
    for (int i = lo + tid; i < hi; i += 256) {
        int rec = binned[i];
        int slot = lo + atomicAdd(&curs[rec & (BIN_SPAN - 1)], 1);
        esrc[slot] = rec;      // keep packed
    }
}

// --------------------------- scalars (layer 1) ------------------------------

__global__ __launch_bounds__(256) void scalars1_kernel(
        const float* __restrict__ x,
        const float* __restrict__ a1b, const float* __restrict__ a1u,
        float* __restrict__ S, __half* __restrict__ xh,
        unsigned char* __restrict__ xq,
        float* __restrict__ XSP, float* __restrict__ XSN, int n) {
    __shared__ float sA[256];
    for (int k = threadIdx.x; k < 256; k += blockDim.x)
        sA[k] = (k < 128) ? a1b[k] : a1u[k - 128];
    __syncthreads();
    int grp = threadIdx.x >> 4, l = threadIdx.x & 15;
    for (int row = blockIdx.x * 16 + grp; row < n; row += gridDim.x * 16) {
        const float4 v = *(const float4*)(x + (size_t)row * 64 + l * 4);
        __half2 h0 = __floats2half2_rn(v.x, v.y);
        __half2 h1 = __floats2half2_rn(v.z, v.w);
        uint2 pk = make_uint2(*(unsigned*)&h0, *(unsigned*)&h1);
        *(uint2*)(xh + (size_t)row * 64 + l * 4) = pk;
        // per-row absmax -> scale s = rowmax/127; int8 biased copy
        float am = fmaxf(fmaxf(fabsf(v.x), fabsf(v.y)), fmaxf(fabsf(v.z), fabsf(v.w)));
        #pragma unroll
        for (int off = 1; off < 16; off <<= 1) am = fmaxf(am, __shfl_xor(am, off));
        am = fmaxf(am, 1e-8f);
        float inv = 127.f / am;
        int q0 = (int)rintf(v.x * inv) + 128;
        int q1 = (int)rintf(v.y * inv) + 128;
        int q2 = (int)rintf(v.z * inv) + 128;
        int q3 = (int)rintf(v.w * inv) + 128;
        unsigned qw = ((unsigned)q0 & 255u) | (((unsigned)q1 & 255u) << 8)
                    | (((unsigned)q2 & 255u) << 16) | (((unsigned)q3 & 255u) << 24);
        *(unsigned*)(xq + (size_t)row * 64 + l * 4) = qw;
        const float4 A0 = *(const float4*)(sA + l * 4);
        const float4 A1 = *(const float4*)(sA + 64 + l * 4);
        const float4 A2 = *(const float4*)(sA + 128 + l * 4);
        const float4 A3 = *(const float4*)(sA + 192 + l * 4);
        float p0 = fmaf(v.x, A0.x, fmaf(v.y, A0.y, fmaf(v.z, A0.z, v.w * A0.w)));
        float p1 = fmaf(v.x, A1.x, fmaf(v.y, A1.y, fmaf(v.z, A1.z, v.w * A1.w)));
        float p2 = fmaf(v.x, A2.x, fmaf(v.y, A2.y, fmaf(v.z, A2.z, v.w * A2.w)));
        float p3 = fmaf(v.x, A3.x, fmaf(v.y, A3.y, fmaf(v.z, A3.z, v.w * A3.w)));
        #pragma unroll
        for (int off = 1; off < 16; off <<= 1) {
            p0 += __shfl_xor(p0, off);
            p1 += __shfl_xor(p1, off);
            p2 += __shfl_xor(p2, off);
            p3 += __shfl_xor(p3, off);
        }
        if (l == 0) {
            float s = am * (1.0f / 127.f);
            S[row] = p0;                          // si pos
            S[2 * (size_t)n + row] = p2;          // si neg
            float e1 = __expf(p1);                // e^sj pos
            float e3 = __expf(p3);                // e^sj neg
            XSP[2 * (size_t)row]     = e1;
            XSP[2 * (size_t)row + 1] = e1 * s;
            XSN[2 * (size_t)row]     = e3;
            XSN[2 * (size_t)row + 1] = e3 * s;
        }
    }
}

// -------- layer 1 aggregation (8-lane group per node, 4 edges in flight) ---

__global__ __launch_bounds__(256) void agg64_kernel(
        const int2* __restrict__ rpA, const int* __restrict__ esA,
        const int2* __restrict__ rpB, const int* __restrict__ esB,
        const float* __restrict__ S,
        const float* __restrict__ XSP, const float* __restrict__ XSN,
        const unsigned char* __restrict__ xq, __half* __restrict__ AGGH1, int n) {
    int gid = blockIdx.x * 32 + (threadIdx.x >> 3);
    int L = threadIdx.x & 7;
    if (gid >= 2 * n) return;
    bool second = gid >= n;
    int node = second ? gid - n : gid;
    const int2*  rp = second ? rpB : rpA;
    const int*   es = second ? esB : esA;
    const float* si = S + (second ? 2 : 0) * (size_t)n;
    const float* xs = second ? XSN : XSP;
    float esi = __expf(si[node]);

    int2 se = rp[node];
    int start = se.x, len = se.y - se.x;
    float a0=0,a1=0,a2=0,a3=0,a4=0,a5=0,a6=0,a7=0;
    float den = 0.f, sden = 0.f;

    int e = 0;
    for (; e + 4 <= len; e += 4) {
        int rec0 = es[start + e];
        int rec1 = es[start + e + 1];
        int rec2 = es[start + e + 2];
        int rec3 = es[start + e + 3];
        int src0 = (int)((unsigned)rec0 >> BIN_SHIFT);
        int src1 = (int)((unsigned)rec1 >> BIN_SHIFT);
        int src2 = (int)((unsigned)rec2 >> BIN_SHIFT);
        int src3 = (int)((unsigned)rec3 >> BIN_SHIFT);
        float2 x20 = *(const float2*)(xs + 2 * (size_t)src0);
        float2 x21 = *(const float2*)(xs + 2 * (size_t)src1);
        float2 x22 = *(const float2*)(xs + 2 * (size_t)src2);
        float2 x23 = *(const float2*)(xs + 2 * (size_t)src3);
        uint2 pk0 = *(const uint2*)(xq + (size_t)src0 * 64 + L * 8);
        uint2 pk1 = *(const uint2*)(xq + (size_t)src1 * 64 + L * 8);
        uint2 pk2 = *(const uint2*)(xq + (size_t)src2 * 64 + L * 8);
        uint2 pk3 = *(const uint2*)(xq + (size_t)src3 * 64 + L * 8);
        float ws0 = esi * x20.y, ws1 = esi * x21.y;
        float ws2 = esi * x22.y, ws3 = esi * x23.y;
        den  += esi * (x20.x + x21.x + x22.x + x23.x);
        sden += ws0 + ws1 + ws2 + ws3;
        a0 = fmaf(ws0, (float)( pk0.x        & 0xffu), a0);
        a1 = fmaf(ws0, (float)((pk0.x >> 8 ) & 0xffu), a1);
        a2 = fmaf(ws0, (float)((pk0.x >> 16) & 0xffu), a2);
        a3 = fmaf(ws0, (float)( pk0.x >> 24        ), a3);
        a4 = fmaf(ws0, (float)( pk0.y        & 0xffu), a4);
        a5 = fmaf(ws0, (float)((pk0.y >> 8 ) & 0xffu), a5);
        a6 = fmaf(ws0, (float)((pk0.y >> 16) & 0xffu), a6);
        a7 = fmaf(ws0, (float)( pk0.y >> 24        ), a7);
        a0 = fmaf(ws1, (float)( pk1.x        & 0xffu), a0);
        a1 = fmaf(ws1, (float)((pk1.x >> 8 ) & 0xffu), a1);
        a2 = fmaf(ws1, (float)((pk1.x >> 16) & 0xffu), a2);
        a3 = fmaf(ws1, (float)( pk1.x >> 24        ), a3);
        a4 = fmaf(ws1, (float)( pk1.y        & 0xffu), a4);
        a5 = fmaf(ws1, (float)((pk1.y >> 8 ) & 0xffu), a5);
        a6 = fmaf(ws1, (float)((pk1.y >> 16) & 0xffu), a6);
        a7 = fmaf(ws1, (float)( pk1.y >> 24        ), a7);
        a0 = fmaf(ws2, (float)( pk2.x        & 0xffu), a0);
        a1 = fmaf(ws2, (float)((pk2.x >> 8 ) & 0xffu), a1);
        a2 = fmaf(ws2, (float)((pk2.x >> 16) & 0xffu), a2);
        a3 = fmaf(ws2, (float)( pk2.x >> 24        ), a3);
        a4 = fmaf(ws2, (float)( pk2.y        & 0xffu), a4);
        a5 = fmaf(ws2, (float)((pk2.y >> 8 ) & 0xffu), a5);
        a6 = fmaf(ws2, (float)((pk2.y >> 16) & 0xffu), a6);
        a7 = fmaf(ws2, (float)( pk2.y >> 24        ), a7);
        a0 = fmaf(ws3, (float)( pk3.x        & 0xffu), a0);
        a1 = fmaf(ws3, (float)((pk3.x >> 8 ) & 0xffu), a1);
        a2 = fmaf(ws3, (float)((pk3.x >> 16) & 0xffu), a2);
        a3 = fmaf(ws3, (float)( pk3.x >> 24        ), a3);
        a4 = fmaf(ws3, (float)( pk3.y        & 0xffu), a4);
        a5 = fmaf(ws3, (float)((pk3.y >> 8 ) & 0xffu), a5);
        a6 = fmaf(ws3, (float)((pk3.y >> 16) & 0xffu), a6);
        a7 = fmaf(ws3, (float)( pk3.y >> 24        ), a7);
    }
    for (; e < len; ++e) {
        int rec0 = es[start + e];
        int src0 = (int)((unsigned)rec0 >> BIN_SHIFT);
        float2 x20 = *(const float2*)(xs + 2 * (size_t)src0);
        uint2 pk0 = *(const uint2*)(xq + (size_t)src0 * 64 + L * 8);
        float ws0 = esi * x20.y;
        den  += esi * x20.x;
        sden += ws0;
        a0 = fmaf(ws0, (float)( pk0.x        & 0xffu), a0);
        a1 = fmaf(ws0, (float)((pk0.x >> 8 ) & 0xffu), a1);
        a2 = fmaf(ws0, (float)((pk0.x >> 16) & 0xffu), a2);
        a3 = fmaf(ws0, (float)( pk0.x >> 24        ), a3);
        a4 = fmaf(ws0, (float)( pk0.y        & 0xffu), a4);
        a5 = fmaf(ws0, (float)((pk0.y >> 8 ) & 0xffu), a5);
        a6 = fmaf(ws0, (float)((pk0.y >> 16) & 0xffu), a6);
        a7 = fmaf(ws0, (float)( pk0.y >> 24        ), a7);
    }
    float r = 1.0f / fmaxf(den, 1e-16f);
    float bd = 128.f * sden;
    __half2 p0 = __floats2half2_rn((a0 - bd) * r, (a1 - bd) * r);
    __half2 p1 = __floats2half2_rn((a2 - bd) * r, (a3 - bd) * r);
    __half2 p2 = __floats2half2_rn((a4 - bd) * r, (a5 - bd) * r);
    __half2 p3 = __floats2half2_rn((a6 - bd) * r, (a7 - bd) * r);
    uint4 pk = make_uint4(*(unsigned*)&p0, *(unsigned*)&p1, *(unsigned*)&p2, *(unsigned*)&p3);
    *(uint4*)(AGGH1 + (size_t)node * 128 + (second ? 64 : 0) + L * 8) = pk;
}

// --------------------- weight packing for MFMA MLPs ------------------------

__global__ __launch_bounds__(256) void pack_weights_kernel(
        const float* __restrict__ W1b, const float* __restrict__ W1u,
        const float* __restrict__ W2b, const float* __restrict__ W2u,
        const float* __restrict__ a2b, const float* __restrict__ a2u,
        __half* __restrict__ WPK1, __half* __restrict__ WPK2,
        __half* __restrict__ A2PK) {
    int t = threadIdx.x;
    for (int i = t; i < 8192; i += 256) {
        int j = i & 7, lane = (i >> 3) & 63, ct = (i >> 9) & 1, kk = (i >> 10) & 3, fam = i >> 12;
        const float* Wx = fam ? W1u : W1b;
        int k = kk * 32 + ((lane >> 4) << 3) + j;
        int col = ct * 16 + (lane & 15);
        WPK1[i] = __float2half(Wx[k * 32 + col]);
    }
    for (int i = t; i < 6144; i += 256) {
        int j = i & 7, lane = (i >> 3) & 63, ct = (i >> 9) & 1;
        int rest = i >> 10;                 // (fam*3 + kk)
        int kk = rest % 3, fam = rest / 3;
        const float* Wx = fam ? W2u : W2b;
        int k = kk * 32 + ((lane >> 4) << 3) + j;
        int col = ct * 16 + (lane & 15);
        WPK2[i] = __float2half(Wx[k * 32 + col]);
    }
    for (int i = t; i < 512; i += 256) {
        int j = i & 7, lane = i >> 3;
        int q = lane & 15, k = ((lane >> 4) << 3) + j;
        float v = 0.f;
        if (q == 0) v = a2b[k];
        else if (q == 1) v = a2b[32 + k];
        else if (q == 2) v = a2u[k];
        else if (q == 3) v = a2u[32 + k];
        A2PK[i] = __float2half(v);
    }
}

// ---------------- layer 1 MLP (MFMA) + tanh + layer-2 scores ---------------

#define ZPITCH 40   // halves; 80B rows keep uint4/half8 accesses 16B-aligned

__global__ __launch_bounds__(256) void mlp1f_kernel(
        const __half* __restrict__ AGGH1, const __half* __restrict__ xh,
        const __half* __restrict__ WPK1, const __half* __restrict__ A2PK,
        const float* __restrict__ b1b, const float* __restrict__ b1u,
        __half* __restrict__ zh, unsigned char* __restrict__ zq,
        float* __restrict__ S, float* __restrict__ SJP2, float* __restrict__ SJN2,
        int n, int ngrp) {
    __shared__ __half zLds[4][16][ZPITCH];
    int w = threadIdx.x >> 6, lane = threadIdx.x & 63;
    int fam = w & 1, l15 = lane & 15, lq = lane >> 4;

    half8 bfrag[4][2];
    #pragma unroll
    for (int kk = 0; kk < 4; ++kk)
        #pragma unroll
        for (int ct = 0; ct < 2; ++ct)
            bfrag[kk][ct] = *(const half8*)(WPK1 + (((fam * 4 + kk) * 2 + ct) << 9) + lane * 8);
    half8 a2frag = *(const half8*)(A2PK + lane * 8);
    const float* bb = fam ? b1u : b1b;
    float bias0 = bb[l15], bias1 = bb[16 + l15];

    int grp = blockIdx.x * 2 + (w >> 1);
    if (grp >= ngrp) return;
    int gbase = grp * 16;
    int arow = gbase + l15; if (arow >= n) arow = n - 1;
    const __half* aggRow = AGGH1 + (size_t)arow * 128 + fam * 64;
    const __half* xRow   = xh   + (size_t)arow * 64;

    f32x4 acc0 = {0.f, 0.f, 0.f, 0.f}, acc1 = {0.f, 0.f, 0.f, 0.f};
    #pragma unroll
    for (int kk = 0; kk < 2; ++kk) {
        half8 a = *(const half8*)(aggRow + kk * 32 + lq * 8);
        acc0 = __builtin_amdgcn_mfma_f32_16x16x32_f16(a, bfrag[kk][0], acc0, 0, 0, 0);
        acc1 = __builtin_amdgcn_mfma_f32_16x16x32_f16(a, bfrag[kk][1], acc1, 0, 0, 0);
    }
    #pragma unroll
    for (int kk = 2; kk < 4; ++kk) {
        half8 a = *(const half8*)(xRow + (kk - 2) * 32 + lq * 8);
        acc0 = __builtin_amdgcn_mfma_f32_16x16x32_f16(a, bfrag[kk][0], acc0, 0, 0, 0);
        acc1 = __builtin_amdgcn_mfma_f32_16x16x32_f16(a, bfrag[kk][1], acc1, 0, 0, 0);
    }
    #pragma unroll
    for (int r = 0; r < 4; ++r) {
        int row = lq * 4 + r;
        zLds[w][row][l15]      = __float2half(tanhf(acc0[r] + bias0));
        zLds[w][row][16 + l15] = __float2half(tanhf(acc1[r] + bias1));
    }
    {
        int node = lane >> 2, chunk = lane & 3;
        int gn = gbase + node;
        uint4 v = *(const uint4*)(&zLds[w][node][chunk * 8]);
        if (gn < n) *(uint4*)(zh + (size_t)gn * 64 + fam * 32 + chunk * 8) = v;
        // int8 copy: biased uint8 q = round(z*127)+128 (z in (-1,1) from tanh)
        const __half* zp = &zLds[w][node][chunk * 8];
        unsigned lo = 0, hi = 0;
        #pragma unroll
        for (int k = 0; k < 4; ++k) {
            int q = (int)rintf(__half2float(zp[k]) * 127.f) + 128;
            lo |= ((unsigned)q & 255u) << (8 * k);
        }
        #pragma unroll
        for (int k = 0; k < 4; ++k) {
            int q = (int)rintf(__half2float(zp[4 + k]) * 127.f) + 128;
            hi |= ((unsigned)q & 255u) << (8 * k);
        }
        if (gn < n) *(uint2*)(zq + (size_t)gn * 64 + fam * 32 + chunk * 8) = make_uint2(lo, hi);
    }
    {
        half8 a = *(const half8*)(&zLds[w][l15][lq * 8]);
        f32x4 sacc = {0.f, 0.f, 0.f, 0.f};
        sacc = __builtin_amdgcn_mfma_f32_16x16x32_f16(a, a2frag, sacc, 0, 0, 0);
        // fam0 (zb): q0->S0(si bp), q1->e^sj bp -> SJP2.x, q2->S6(si un),
        //            q3->e^sj un -> SJN2.x
        // fam1 (zu): q0->S2(si bn), q1->e^sj bn -> SJN2.y, q2->S4(si up),
        //            q3->e^sj up -> SJP2.y
        if (l15 < 4) {
            #pragma unroll
            for (int r = 0; r < 4; ++r) {
                int node = gbase + lq * 4 + r;
                if (node >= n) continue;
                float v = sacc[r];
                if (fam == 0) {
                    if (l15 == 0)      S[node] = v;
                    else if (l15 == 1) SJP2[2 * (size_t)node]     = __expf(v);
                    else if (l15 == 2) S[6 * (size_t)n + node] = v;
                    else               SJN2[2 * (size_t)node]     = __expf(v);
                } else {
                    if (l15 == 0)      S[2 * (size_t)n + node] = v;
                    else if (l15 == 1) SJN2[2 * (size_t)node + 1] = __expf(v);
                    else if (l15 == 2) S[4 * (size_t)n + node] = v;
                    else               SJP2[2 * (size_t)node + 1] = __expf(v);
                }
            }
        }
    }
}

// ------- layer 2 aggregation (8-lane group per node, 4 edges in flight) ----

// AGGH row layout per node: [bp(32) | bn(32) | up(32) | un(32)] fp16.
// Lane L<4 accumulates L family (bytes L*8 of zq = zb cols), L>=4 H family.
__global__ __launch_bounds__(256) void agg32pair_kernel(
        const int2* __restrict__ rpA, const int* __restrict__ esA,
        const int2* __restrict__ rpB, const int* __restrict__ esB,
        const float* __restrict__ S,
        const float* __restrict__ SJP2, const float* __restrict__ SJN2,
        const unsigned char* __restrict__ zq, __half* __restrict__ AGGH, int n) {
    int gid = blockIdx.x * 32 + (threadIdx.x >> 3);
    int L = threadIdx.x & 7;
    if (gid >= 2 * n) return;
    bool second = gid >= n;
    int node = second ? gid - n : gid;
    const int2* rp = second ? rpB : rpA;
    const int*  es = second ? esB : esA;
    // pos: L=bp(si S0) H=up(si S4).  neg: L=un(si S6) H=bn(si S2).
    const float* siL = S + (second ? 6 : 0) * (size_t)n;
    const float* siH = S + (second ? 2 : 4) * (size_t)n;
    const float* sj2 = second ? SJN2 : SJP2;
    float esiL = __expf(siL[node]), esiH = __expf(siH[node]);
    bool lowf = L < 4;
    float esiF = lowf ? esiL : esiH;

    int2 se = rp[node];
    int start = se.x, len = se.y - se.x;
    float a0=0,a1=0,a2=0,a3=0,a4=0,a5=0,a6=0,a7=0;
    float denL = 0.f, denH = 0.f;

    int e = 0;
    for (; e + 4 <= len; e += 4) {
        int rec0 = es[start + e];
        int rec1 = es[start + e + 1];
        int rec2 = es[start + e + 2];
        int rec3 = es[start + e + 3];
        int src0 = (int)((unsigned)rec0 >> BIN_SHIFT);
        int src1 = (int)((unsigned)rec1 >> BIN_SHIFT);
        int src2 = (int)((unsigned)rec2 >> BIN_SHIFT);
        int src3 = (int)((unsigned)rec3 >> BIN_SHIFT);
        float2 e20 = *(const float2*)(sj2 + 2 * (size_t)src0);
        float2 e21 = *(const float2*)(sj2 + 2 * (size_t)src1);
        float2 e22 = *(const float2*)(sj2 + 2 * (size_t)src2);
        float2 e23 = *(const float2*)(sj2 + 2 * (size_t)src3);
        uint2 pk0 = *(const uint2*)(zq + (size_t)src0 * 64 + L * 8);
        uint2 pk1 = *(const uint2*)(zq + (size_t)src1 * 64 + L * 8);
        uint2 pk2 = *(const uint2*)(zq + (size_t)src2 * 64 + L * 8);
        uint2 pk3 = *(const uint2*)(zq + (size_t)src3 * 64 + L * 8);
        denL += esiL * (e20.x + e21.x + e22.x + e23.x);
        denH += esiH * (e20.y + e21.y + e22.y + e23.y);
        float wt0 = esiF * (lowf ? e20.x : e20.y);
        float wt1 = esiF * (lowf ? e21.x : e21.y);
        float wt2 = esiF * (lowf ? e22.x : e22.y);
        float wt3 = esiF * (lowf ? e23.x : e23.y);
        a0 = fmaf(wt0, (float)( pk0.x        & 0xffu), a0);
        a1 = fmaf(wt0, (float)((pk0.x >> 8 ) & 0xffu), a1);
        a2 = fmaf(wt0, (float)((pk0.x >> 16) & 0xffu), a2);
        a3 = fmaf(wt0, (float)( pk0.x >> 24        ), a3);
        a4 = fmaf(wt0, (float)( pk0.y        & 0xffu), a4);
        a5 = fmaf(wt0, (float)((pk0.y >> 8 ) & 0xffu), a5);
        a6 = fmaf(wt0, (float)((pk0.y >> 16) & 0xffu), a6);
        a7 = fmaf(wt0, (float)( pk0.y >> 24        ), a7);
        a0 = fmaf(wt1, (float)( pk1.x        & 0xffu), a0);
        a1 = fmaf(wt1, (float)((pk1.x >> 8 ) & 0xffu), a1);
        a2 = fmaf(wt1, (float)((pk1.x >> 16) & 0xffu), a2);
        a3 = fmaf(wt1, (float)( pk1.x >> 24        ), a3);
        a4 = fmaf(wt1, (float)( pk1.y        & 0xffu), a4);
        a5 = fmaf(wt1, (float)((pk1.y >> 8 ) & 0xffu), a5);
        a6 = fmaf(wt1, (float)((pk1.y >> 16) & 0xffu), a6);
        a7 = fmaf(wt1, (float)( pk1.y >> 24        ), a7);
        a0 = fmaf(wt2, (float)( pk2.x        & 0xffu), a0);
        a1 = fmaf(wt2, (float)((pk2.x >> 8 ) & 0xffu), a1);
        a2 = fmaf(wt2, (float)((pk2.x >> 16) & 0xffu), a2);
        a3 = fmaf(wt2, (float)( pk2.x >> 24        ), a3);
        a4 = fmaf(wt2, (float)( pk2.y        & 0xffu), a4);
        a5 = fmaf(wt2, (float)((pk2.y >> 8 ) & 0xffu), a5);
        a6 = fmaf(wt2, (float)((pk2.y >> 16) & 0xffu), a6);
        a7 = fmaf(wt2, (float)( pk2.y >> 24        ), a7);
        a0 = fmaf(wt3, (float)( pk3.x        & 0xffu), a0);
        a1 = fmaf(wt3, (float)((pk3.x >> 8 ) & 0xffu), a1);
        a2 = fmaf(wt3, (float)((pk3.x >> 16) & 0xffu), a2);
        a3 = fmaf(wt3, (float)( pk3.x >> 24        ), a3);
        a4 = fmaf(wt3, (float)( pk3.y        & 0xffu), a4);
        a5 = fmaf(wt3, (float)((pk3.y >> 8 ) & 0xffu), a5);
        a6 = fmaf(wt3, (float)((pk3.y >> 16) & 0xffu), a6);
        a7 = fmaf(wt3, (float)( pk3.y >> 24        ), a7);
    }
    for (; e < len; ++e) {
        int rec0 = es[start + e];
        int src0 = (int)((unsigned)rec0 >> BIN_SHIFT);
        float2 e20 = *(const float2*)(sj2 + 2 * (size_t)src0);
        uint2 pk0 = *(const uint2*)(zq + (size_t)src0 * 64 + L * 8);
        denL += esiL * e20.x;
        denH += esiH * e20.y;
        float wt0 = esiF * (lowf ? e20.x : e20.y);
        a0 = fmaf(wt0, (float)( pk0.x        & 0xffu), a0);
        a1 = fmaf(wt0, (float)((pk0.x >> 8 ) & 0xffu), a1);
        a2 = fmaf(wt0, (float)((pk0.x >> 16) & 0xffu), a2);
        a3 = fmaf(wt0, (float)( pk0.x >> 24        ), a3);
        a4 = fmaf(wt0, (float)( pk0.y        & 0xffu), a4);
        a5 = fmaf(wt0, (float)((pk0.y >> 8 ) & 0xffu), a5);
        a6 = fmaf(wt0, (float)((pk0.y >> 16) & 0xffu), a6);
        a7 = fmaf(wt0, (float)( pk0.y >> 24        ), a7);
    }
    float d = lowf ? denL : denH;
    float r = (d > 0.f) ? (1.0f / d) : 0.f;
    const float c = 1.0f / 127.0f;
    float bd = 128.f * d;
    float o0 = (a0 - bd) * r * c, o1 = (a1 - bd) * r * c;
    float o2 = (a2 - bd) * r * c, o3 = (a3 - bd) * r * c;
    float o4 = (a4 - bd) * r * c, o5 = (a5 - bd) * r * c;
    float o6 = (a6 - bd) * r * c, o7 = (a7 - bd) * r * c;
    __half2 p0 = __floats2half2_rn(o0, o1);
    __half2 p1 = __floats2half2_rn(o2, o3);
    __half2 p2 = __floats2half2_rn(o4, o5);
    __half2 p3 = __floats2half2_rn(o6, o7);
    uint4 pk = make_uint4(*(unsigned*)&p0, *(unsigned*)&p1, *(unsigned*)&p2, *(unsigned*)&p3);
    // pos: L=bp->0, H=up->64 ; neg: L=un->96, H=bn->32
    int base = second ? (lowf ? 96 : 32) : (lowf ? 0 : 64);
    *(uint4*)(AGGH + (size_t)node * 128 + base + (L & 3) * 8) = pk;
}

// ------------------------------ MLP 2 (MFMA) -------------------------------

__global__ __launch_bounds__(256) void mlp2_kernel(
        const __half* __restrict__ AGGH, const __half* __restrict__ zh,
        const __half* __restrict__ WPK2,
        const float* __restrict__ b2b, const float* __restrict__ b2u,
        float* __restrict__ out, int n, int ngrp) {
    int w = threadIdx.x >> 6, lane = threadIdx.x & 63;
    int fam = w & 1, l15 = lane & 15, lq = lane >> 4;

    half8 bfrag[3][2];
    #pragma unroll
    for (int kk = 0; kk < 3; ++kk)
        #pragma unroll
        for (int ct = 0; ct < 2; ++ct)
            bfrag[kk][ct] = *(const half8*)(WPK2 + (((fam * 3 + kk) * 2 + ct) << 9) + lane * 8);
    const float* bb = fam ? b2u : b2b;
    float bias0 = bb[l15], bias1 = bb[16 + l15];

    int grp = blockIdx.x * 2 + (w >> 1);
    if (grp >= ngrp) return;
    int gbase = grp * 16;
    int arow = gbase + l15; if (arow >= n) arow = n - 1;
    const __half* aggRow = AGGH + (size_t)arow * 128 + fam * 64;
    const __half* zRow   = zh   + (size_t)arow * 64 + fam * 32;

    f32x4 acc0 = {0.f, 0.f, 0.f, 0.f}, acc1 = {0.f, 0.f, 0.f, 0.f};
    #pragma unroll
    for (int kk = 0; kk < 2; ++kk) {
        half8 a = *(const half8*)(aggRow + kk * 32 + lq * 8);
        acc0 = __builtin_amdgcn_mfma_f32_16x16x32_f16(a, bfrag[kk][0], acc0, 0, 0, 0);
        acc1 = __builtin_amdgcn_mfma_f32_16x16x32_f16(a, bfrag[kk][1], acc1, 0, 0, 0);
    }
    {
        half8 a = *(const half8*)(zRow + lq * 8);
        acc0 = __builtin_amdgcn_mfma_f32_16x16x32_f16(a, bfrag[2][0], acc0, 0, 0, 0);
        acc1 = __builtin_amdgcn_mfma_f32_16x16x32_f16(a, bfrag[2][1], acc1, 0, 0, 0);
    }
    #pragma unroll
    for (int r = 0; r < 4; ++r) {
        int node = gbase + lq * 4 + r;
        if (node < n) {
            out[(size_t)node * 64 + fam * 32 + l15]      = tanhf(acc0[r] + bias0);
            out[(size_t)node * 64 + fam * 32 + 16 + l15] = tanhf(acc1[r] + bias1);
        }
    }
}

// ------------------------------ launcher -----------------------------------

extern "C" void kernel_launch(void* const* d_in, const int* in_sizes, int n_in,
                              void* d_out, int out_size, void* d_ws, size_t ws_size,
                              hipStream_t stream) {
    const float* x   = (const float*)d_in[0];
    const int*   pos = (const int*)d_in[1];
    const int*   neg = (const int*)d_in[2];
    const float* a1b = (const float*)d_in[3];
    const float* a1u = (const float*)d_in[4];
    const float* W1b = (const float*)d_in[5];
    const float* b1b = (const float*)d_in[6];
    const float* W1u = (const float*)d_in[7];
    const float* b1u = (const float*)d_in[8];
    const float* a2b = (const float*)d_in[9];
    const float* a2u = (const float*)d_in[10];
    const float* W2b = (const float*)d_in[11];
    const float* b2b = (const float*)d_in[12];
    const float* W2u = (const float*)d_in[13];
    const float* b2u = (const float*)d_in[14];
    float* out = (float*)d_out;

    const int n  = in_sizes[0] / 64;
    const int Ep = in_sizes[1] / 2;
    const int En = in_sizes[2] / 2;
    const int* ps = pos;  const int* pd = pos + Ep;
    const int* ns = neg;  const int* nd = neg + En;
    const int nbin = (n + BIN_SPAN - 1) >> BIN_SHIFT;   // 391 for n=100000
    const int ngrp = (n + 15) / 16;

    // ws layout (4-byte words)
    unsigned* W = (unsigned*)d_ws;
    size_t o = 0;
    float* S        = (float*)(W + o); o += 8 * (size_t)n;
    int2*  rowptrP  = (int2*)(W + o);  o += 2 * (size_t)n;
    int2*  rowptrN  = (int2*)(W + o);  o += 2 * (size_t)n;
    int*   binCntP  = (int*)(W + o);   o += nbin;
    int*   binCntN  = (int*)(W + o);   o += nbin;
    int*   binBaseP = (int*)(W + o);   o += nbin + 1;
    int*   binBaseN = (int*)(W + o);   o += nbin + 1;
    int*   gCurP    = (int*)(W + o);   o += nbin;
    int*   gCurN    = (int*)(W + o);   o += nbin;
    int*   esrcP    = (int*)(W + o);   o += Ep;
    int*   esrcN    = (int*)(W + o);   o += En;
    o = (o + 1) & ~(size_t)1;
    float* XSP      = (float*)(W + o); o += 2 * (size_t)n;   // (e^sj, e^sj*rscl) pos
    float* XSN      = (float*)(W + o); o += 2 * (size_t)n;   // (e^sj, e^sj*rscl) neg
    float* SJP2     = (float*)(W + o); o += 2 * (size_t)n;   // (e^sjL, e^sjH) pos
    float* SJN2     = (float*)(W + o); o += 2 * (size_t)n;   // (e^sjL, e^sjH) neg
    o = (o + 3) & ~(size_t)3;
    __half* XH      = (__half*)(W + o); o += 32 * (size_t)n;   // x rows fp16
    __half* ZH      = (__half*)(W + o); o += 32 * (size_t)n;   // z rows fp16
    unsigned char* XQ = (unsigned char*)(W + o); o += 16 * (size_t)n; // x rows u8
    unsigned char* ZQ = (unsigned char*)(W + o); o += 16 * (size_t)n; // z rows u8
    o = (o + 3) & ~(size_t)3;
    __half* WPK1    = (__half*)(W + o); o += 4096;
    __half* WPK2    = (__half*)(W + o); o += 3072;
    __half* A2PK    = (__half*)(W + o); o += 256;
    o = (o + 3) & ~(size_t)3;
    __half* AGGH    = (__half*)(W + o); o += 64 * (size_t)n;   // [n][128] fp16
    int*   binnedP  = (int*)AGGH;        // CSR-build scratch aliases AGGH
    int*   binnedN  = binnedP + Ep;
    __half* AGGH1   = AGGH;              // layer-1 agg rows [aggP|aggN]

    const int B = 256;
    const int aggBlocks = (2 * n + 31) / 32;
    const int mlpBlocks = (ngrp + 1) / 2;
    const int nbP = (Ep + 4095) / 4096, nbN = (En + 4095) / 4096;

    // -------- scalars + pack + merged CSR build ------
    hipMemsetAsync(binCntP, 0, 2 * (size_t)nbin * sizeof(int), stream);
    pack_weights_kernel<<<1, 256, 0, stream>>>(W1b, W1u, W2b, W2u, a2b, a2u,
                                               WPK1, WPK2, A2PK);
    scalars1_kernel<<<512, B, 0, stream>>>(x, a1b, a1u, S, XH, XQ, XSP, XSN, n);
    bin_hist2_kernel<<<304, B, 0, stream>>>(pd, Ep, nd, En, binCntP, binCntN, nbin);
    scan_bins2_kernel<<<2, 512, 0, stream>>>(binCntP, binCntN, nbin,
                                             binBaseP, binBaseN, gCurP, gCurN);
    bin_scatter2_kernel<<<nbP + nbN, 256, 0, stream>>>(
        ps, pd, Ep, binBaseP, gCurP, binnedP,
        ns, nd, En, binBaseN, gCurN, binnedN, nbin, nbP);
    bin_finalize2_kernel<<<2 * nbin, 256, 0, stream>>>(
        binnedP, binBaseP, rowptrP, esrcP,
        binnedN, binBaseN, rowptrN, esrcN, n, nbin);

    // ---------------- Layer 1 ----------------
    agg64_kernel<<<aggBlocks, 256, 0, stream>>>(
        rowptrP, esrcP, rowptrN, esrcN, S, XSP, XSN, XQ, AGGH1, n);
    mlp1f_kernel<<<mlpBlocks, 256, 0, stream>>>(AGGH1, XH, WPK1, A2PK,
                                                b1b, b1u, ZH, ZQ, S, SJP2, SJN2,
                                                n, ngrp);

    // ---------------- Layer 2 ----------------
    agg32pair_kernel<<<aggBlocks, 256, 0, stream>>>(
        rowptrP, esrcP, rowptrN, esrcN, S, SJP2, SJN2, ZQ, AGGH, n);
    mlp2_kernel<<<mlpBlocks, 256, 0, stream>>>(AGGH, ZH, WPK2, b2b, b2u, out, n, ngrp);
}